// Round 1
// baseline (1147.581 us; speedup 1.0000x reference)
//
#include <hip/hip_runtime.h>

#define N_NODES 100000
#define N_EDGES 3200000
#define G_GRAPHS 512
#define HDIM 64

// ---------------------------------------------------------------- init
__global__ void k0_init(int* __restrict__ deg, float* __restrict__ pool,
                        int* __restrict__ cnt) {
    int i = blockIdx.x * blockDim.x + threadIdx.x;
    if (i < N_NODES) deg[i] = 1;                 // self-loop
    if (i < G_GRAPHS * HDIM) pool[i] = 0.f;
    if (i < G_GRAPHS) cnt[i] = 0;
}

// ---------------------------------------------------------------- degree
__global__ void k1_deg(const int* __restrict__ dst, int* __restrict__ deg) {
    int e = blockIdx.x * blockDim.x + threadIdx.x;
    if (e < N_EDGES) atomicAdd(&deg[dst[e]], 1);
}

// ------------------------------------------------- dis = rsqrt(deg), agg1 init
__global__ void k2_dis(const int* __restrict__ deg, const float* __restrict__ x,
                       float* __restrict__ dis, float* __restrict__ agg1) {
    int n = blockIdx.x * blockDim.x + threadIdx.x;
    if (n < N_NODES) {
        float d = (float)deg[n];          // >= 1 always (self loop)
        dis[n] = rsqrtf(d);
        agg1[n] = x[n] / d;               // self-loop term: dis^2 * x
    }
}

// ---------------------------------------------------------------- layer-1 scalar aggregation
__global__ void k3_agg1(const int* __restrict__ src, const int* __restrict__ dst,
                        const float* __restrict__ dis, const float* __restrict__ x,
                        float* __restrict__ agg1) {
    int e = blockIdx.x * blockDim.x + threadIdx.x;
    if (e < N_EDGES) {
        int s = src[e], d = dst[e];
        atomicAdd(&agg1[d], dis[s] * dis[d] * x[s]);
    }
}

// ------------------------------------------ agg2 self-loop init: dis^2 * relu(agg1*W1+b1)
__global__ void k4_agg2init(const float* __restrict__ agg1, const float* __restrict__ dis,
                            const float* __restrict__ W1, const float* __restrict__ b1,
                            float* __restrict__ agg2) {
    int i = blockIdx.x * blockDim.x + threadIdx.x;   // i = n*64 + j
    if (i < N_NODES * HDIM) {
        int n = i >> 6, j = i & 63;
        float h = fmaxf(agg1[n] * W1[j] + b1[j], 0.f);
        float r = dis[n];
        agg2[i] = r * r * h;
    }
}

// ---------------------------------------------------------------- layer-2 edge scatter
// one wave per edge; lane = channel j. h1[s,j] recomputed on the fly from agg1[s].
__global__ void k5_edge(const int* __restrict__ src, const int* __restrict__ dst,
                        const float* __restrict__ dis, const float* __restrict__ agg1,
                        const float* __restrict__ W1, const float* __restrict__ b1,
                        float* __restrict__ agg2) {
    int t = blockIdx.x * blockDim.x + threadIdx.x;   // < E*64 = 204.8M < 2^31
    int e = t >> 6;
    int j = t & 63;
    if (e < N_EDGES) {
        int s = src[e], d = dst[e];                  // wave-uniform broadcast loads
        float w = dis[s] * dis[d];
        float h = fmaxf(agg1[s] * W1[j] + b1[j], 0.f);
        atomicAdd(&agg2[d * HDIM + j], w * h);       // coalesced 256B per wave
    }
}

// ---------------------------------------- h2 = relu(agg2 @ W2 + b2); pool-sum by graph
__global__ void k6_pool(const float* __restrict__ agg2, const float* __restrict__ W2,
                        const float* __restrict__ b2, const int* __restrict__ batch,
                        float* __restrict__ pool, int* __restrict__ cnt) {
    __shared__ float w2s[HDIM * HDIM];               // 16 KB
    int tid = threadIdx.x;
    for (int i = tid; i < HDIM * HDIM; i += blockDim.x) w2s[i] = W2[i];
    __syncthreads();
    int lane = tid & 63;
    int wid  = tid >> 6;                             // 0..3
    int nwaves = gridDim.x * 4;
    for (int n = blockIdx.x * 4 + wid; n < N_NODES; n += nwaves) {
        float av  = agg2[n * HDIM + lane];           // coalesced row load
        float acc = b2[lane];
        #pragma unroll
        for (int k = 0; k < HDIM; ++k) {
            acc += __shfl(av, k, 64) * w2s[k * HDIM + lane];   // lane-stride-1: conflict-free
        }
        acc = fmaxf(acc, 0.f);
        int g = batch[n];
        atomicAdd(&pool[g * HDIM + lane], acc);
        if (lane == 0) atomicAdd(&cnt[g], 1);
    }
}

// ---------------------------------------------------------------- final MLP per graph
__global__ void k7_mlp(const float* __restrict__ pool, const int* __restrict__ cnt,
                       const float* __restrict__ fW1, const float* __restrict__ fb1,
                       const float* __restrict__ fW2, const float* __restrict__ fb2,
                       float* __restrict__ out) {
    __shared__ float p[HDIM];
    __shared__ float tt[32];
    int g = blockIdx.x;
    int tid = threadIdx.x;
    float c = fmaxf((float)cnt[g], 1.f);
    p[tid] = pool[g * HDIM + tid] / c;
    __syncthreads();
    if (tid < 32) {
        float acc = fb1[tid];
        #pragma unroll
        for (int j = 0; j < HDIM; ++j) acc += p[j] * fW1[j * 32 + tid];
        tt[tid] = fmaxf(acc, 0.f);
    }
    __syncthreads();
    if (tid < 7) {
        float acc = fb2[tid];
        #pragma unroll
        for (int i = 0; i < 32; ++i) acc += tt[i] * fW2[i * 7 + tid];
        out[g * 7 + tid] = acc;
    }
}

// ----------------------------------------------------------------------------
extern "C" void kernel_launch(void* const* d_in, const int* in_sizes, int n_in,
                              void* d_out, int out_size, void* d_ws, size_t ws_size,
                              hipStream_t stream) {
    const float* x    = (const float*)d_in[0];
    const int*   ei   = (const int*)  d_in[1];
    const int*   batch= (const int*)  d_in[2];
    const float* W1   = (const float*)d_in[3];
    const float* b1   = (const float*)d_in[4];
    const float* W2   = (const float*)d_in[5];
    const float* b2   = (const float*)d_in[6];
    const float* fW1  = (const float*)d_in[7];
    const float* fb1  = (const float*)d_in[8];
    const float* fW2  = (const float*)d_in[9];
    const float* fb2  = (const float*)d_in[10];
    const int* src = ei;
    const int* dst = ei + N_EDGES;
    float* out = (float*)d_out;

    char* ws = (char*)d_ws;
    int*   deg  = (int*)ws;   ws += (size_t)N_NODES * 4;
    float* dis  = (float*)ws; ws += (size_t)N_NODES * 4;
    float* agg1 = (float*)ws; ws += (size_t)N_NODES * 4;
    float* agg2 = (float*)ws; ws += (size_t)N_NODES * HDIM * 4;
    float* pool = (float*)ws; ws += (size_t)G_GRAPHS * HDIM * 4;
    int*   cnt  = (int*)ws;   ws += (size_t)G_GRAPHS * 4;

    k0_init<<<(N_NODES + 255) / 256, 256, 0, stream>>>(deg, pool, cnt);
    k1_deg<<<(N_EDGES + 255) / 256, 256, 0, stream>>>(dst, deg);
    k2_dis<<<(N_NODES + 255) / 256, 256, 0, stream>>>(deg, x, dis, agg1);
    k3_agg1<<<(N_EDGES + 255) / 256, 256, 0, stream>>>(src, dst, dis, x, agg1);
    k4_agg2init<<<(N_NODES * HDIM + 255) / 256, 256, 0, stream>>>(agg1, dis, W1, b1, agg2);
    int nthreads_k5_blocks = (int)(((long long)N_EDGES * HDIM + 255) / 256);
    k5_edge<<<nthreads_k5_blocks, 256, 0, stream>>>(src, dst, dis, agg1, W1, b1, agg2);
    k6_pool<<<2048, 256, 0, stream>>>(agg2, W2, b2, batch, pool, cnt);
    k7_mlp<<<G_GRAPHS, 64, 0, stream>>>(pool, cnt, fW1, fb1, fW2, fb2, out);
}

// Round 2
// 816.759 us; speedup vs baseline: 1.4050x; 1.4050x over previous
//
#include <hip/hip_runtime.h>

#define N_NODES 100000
#define N_EDGES 3200000
#define G_GRAPHS 512
#define HDIM 64
#define NBUCK 65   // 64 thresholds -> 65 buckets

// ---------------------------------------------------------------- degree
__global__ void k1_deg(const int* __restrict__ dst, int* __restrict__ deg) {
    int e = blockIdx.x * blockDim.x + threadIdx.x;
    if (e < N_EDGES) atomicAdd(&deg[dst[e]], 1);
}

// -------------------------------------------- dis = rsqrt(deg+1), agg1 self-loop init
__global__ void k2_dis(const int* __restrict__ deg, const float* __restrict__ x,
                       float* __restrict__ dis, float* __restrict__ agg1) {
    int n = blockIdx.x * blockDim.x + threadIdx.x;
    if (n < N_NODES) {
        float d = (float)(deg[n] + 1);    // +1 self-loop (deg memset to 0)
        dis[n] = rsqrtf(d);
        agg1[n] = x[n] / d;               // self-loop term: dis^2 * x
    }
}

// ---------------------------------------------------------------- layer-1 scalar aggregation
__global__ void k3_agg1(const int* __restrict__ src, const int* __restrict__ dst,
                        const float* __restrict__ dis, const float* __restrict__ x,
                        float* __restrict__ agg1) {
    int e = blockIdx.x * blockDim.x + threadIdx.x;
    if (e < N_EDGES) {
        int s = src[e], d = dst[e];
        atomicAdd(&agg1[d], dis[s] * dis[d] * x[s]);
    }
}

// ------------------------------------------- per-channel relu thresholds, stable sort + ranks
__global__ void kprep(const float* __restrict__ W1, const float* __restrict__ b1,
                      float* __restrict__ sorted_t, int* __restrict__ rankArr) {
    __shared__ float ts[HDIM];
    int j = threadIdx.x;
    float w1 = W1[j], bb = b1[j];
    float tj = (w1 != 0.f) ? (-bb / w1) : 0.f;   // w1==0 rank unused; keep finite
    ts[j] = tj;
    __syncthreads();
    int r = 0;
    for (int i = 0; i < HDIM; ++i) {
        float ti = ts[i];
        if (ti < tj || (ti == tj && i < j)) r++;   // stable rank
    }
    sorted_t[r] = tj;
    rankArr[j] = r;
}

// ------------------------------------- layer-2 edge scatter: 2 atomics/edge into 65 buckets
__global__ void k5_bucket(const int* __restrict__ src, const int* __restrict__ dst,
                          const float* __restrict__ dis, const float* __restrict__ agg1,
                          const float* __restrict__ sorted_t, float* __restrict__ hist) {
    __shared__ float ts[HDIM];
    if (threadIdx.x < HDIM) ts[threadIdx.x] = sorted_t[threadIdx.x];
    __syncthreads();
    int e = blockIdx.x * blockDim.x + threadIdx.x;
    if (e < N_EDGES) {
        int s = src[e], d = dst[e];
        float a = agg1[s];
        float w = dis[s] * dis[d];
        // k = #{thresholds < a} in [0,64] via branchless binary search (7 levels)
        int k = 0;
        #pragma unroll
        for (int step = 64; step >= 1; step >>= 1) {
            int m = k + step;
            if (m <= HDIM && ts[m - 1] < a) k = m;
        }
        float* h = &hist[((size_t)d * NBUCK + k) * 2];
        atomicAdd(h,     w * a);
        atomicAdd(h + 1, w);
    }
}

// ----- fused: reconstruct agg2 row from bucket scans + self-loop, @W2+b2, relu, pool
__global__ void knode(const float2* __restrict__ hist2, const int* __restrict__ rankArr,
                      const float* __restrict__ W1, const float* __restrict__ b1,
                      const float* __restrict__ agg1, const float* __restrict__ dis,
                      const float* __restrict__ W2, const float* __restrict__ b2,
                      const int* __restrict__ batch,
                      float* __restrict__ pool, int* __restrict__ cnt) {
    __shared__ float w2s[HDIM * HDIM];               // 16 KB
    int tid = threadIdx.x;
    for (int i = tid; i < HDIM * HDIM; i += blockDim.x) w2s[i] = W2[i];
    __syncthreads();
    int lane = tid & 63, wid = tid >> 6;
    float w1 = W1[lane], bb = b1[lane];
    int r = rankArr[lane];
    float bB2 = b2[lane];
    int nwaves = gridDim.x * 4;
    for (int n = blockIdx.x * 4 + wid; n < N_NODES; n += nwaves) {
        float2 hv  = hist2[(size_t)n * NBUCK + lane];   // bucket `lane`
        float2 h64 = hist2[(size_t)n * NBUCK + 64];     // bucket 64 (uniform)
        float PA = hv.x, PW = hv.y;                     // inclusive scans over buckets 0..63
        #pragma unroll
        for (int off = 1; off < 64; off <<= 1) {
            float tA = __shfl_up(PA, off, 64);
            float tW = __shfl_up(PW, off, 64);
            if (lane >= off) { PA += tA; PW += tW; }
        }
        float TA = __shfl(PA, 63, 64) + h64.x;          // totals incl bucket 64
        float TW = __shfl(PW, 63, 64) + h64.y;
        float sA = __shfl(PA, r, 64);                   // prefix up to rank r
        float sW = __shfl(PW, r, 64);
        float agg2j;
        if (w1 > 0.f)      agg2j = w1 * (TA - sA) + bb * (TW - sW);  // active: a > t
        else if (w1 < 0.f) agg2j = w1 * sA + bb * sW;                // active: a < t
        else               agg2j = fmaxf(bb, 0.f) * TW;              // constant channel
        float dn = dis[n];
        agg2j += dn * dn * fmaxf(agg1[n] * w1 + bb, 0.f);            // self-loop
        // h2 = relu(agg2 @ W2 + b2), then pool
        float acc = bB2;
        #pragma unroll
        for (int kk = 0; kk < HDIM; ++kk)
            acc += __shfl(agg2j, kk, 64) * w2s[kk * HDIM + lane];
        acc = fmaxf(acc, 0.f);
        int g = batch[n];
        atomicAdd(&pool[(size_t)g * HDIM + lane], acc);
        if (lane == 0) atomicAdd(&cnt[g], 1);
    }
}

// ---------------------------------------------------------------- final MLP per graph
__global__ void k7_mlp(const float* __restrict__ pool, const int* __restrict__ cnt,
                       const float* __restrict__ fW1, const float* __restrict__ fb1,
                       const float* __restrict__ fW2, const float* __restrict__ fb2,
                       float* __restrict__ out) {
    __shared__ float p[HDIM];
    __shared__ float tt[32];
    int g = blockIdx.x;
    int tid = threadIdx.x;
    float c = fmaxf((float)cnt[g], 1.f);
    p[tid] = pool[g * HDIM + tid] / c;
    __syncthreads();
    if (tid < 32) {
        float acc = fb1[tid];
        #pragma unroll
        for (int j = 0; j < HDIM; ++j) acc += p[j] * fW1[j * 32 + tid];
        tt[tid] = fmaxf(acc, 0.f);
    }
    __syncthreads();
    if (tid < 7) {
        float acc = fb2[tid];
        #pragma unroll
        for (int i = 0; i < 32; ++i) acc += tt[i] * fW2[i * 7 + tid];
        out[g * 7 + tid] = acc;
    }
}

// =================== fallback path (round-1 kernels, used if ws too small) ===================
__global__ void k4_agg2init(const float* __restrict__ agg1, const float* __restrict__ dis,
                            const float* __restrict__ W1, const float* __restrict__ b1,
                            float* __restrict__ agg2) {
    int i = blockIdx.x * blockDim.x + threadIdx.x;
    if (i < N_NODES * HDIM) {
        int n = i >> 6, j = i & 63;
        float h = fmaxf(agg1[n] * W1[j] + b1[j], 0.f);
        float r = dis[n];
        agg2[i] = r * r * h;
    }
}

__global__ void k5_edge(const int* __restrict__ src, const int* __restrict__ dst,
                        const float* __restrict__ dis, const float* __restrict__ agg1,
                        const float* __restrict__ W1, const float* __restrict__ b1,
                        float* __restrict__ agg2) {
    int t = blockIdx.x * blockDim.x + threadIdx.x;
    int e = t >> 6;
    int j = t & 63;
    if (e < N_EDGES) {
        int s = src[e], d = dst[e];
        float w = dis[s] * dis[d];
        float h = fmaxf(agg1[s] * W1[j] + b1[j], 0.f);
        atomicAdd(&agg2[d * HDIM + j], w * h);
    }
}

__global__ void k6_pool(const float* __restrict__ agg2, const float* __restrict__ W2,
                        const float* __restrict__ b2, const int* __restrict__ batch,
                        float* __restrict__ pool, int* __restrict__ cnt) {
    __shared__ float w2s[HDIM * HDIM];
    int tid = threadIdx.x;
    for (int i = tid; i < HDIM * HDIM; i += blockDim.x) w2s[i] = W2[i];
    __syncthreads();
    int lane = tid & 63;
    int wid  = tid >> 6;
    int nwaves = gridDim.x * 4;
    for (int n = blockIdx.x * 4 + wid; n < N_NODES; n += nwaves) {
        float av  = agg2[n * HDIM + lane];
        float acc = b2[lane];
        #pragma unroll
        for (int k = 0; k < HDIM; ++k)
            acc += __shfl(av, k, 64) * w2s[k * HDIM + lane];
        acc = fmaxf(acc, 0.f);
        int g = batch[n];
        atomicAdd(&pool[g * HDIM + lane], acc);
        if (lane == 0) atomicAdd(&cnt[g], 1);
    }
}

// ----------------------------------------------------------------------------
extern "C" void kernel_launch(void* const* d_in, const int* in_sizes, int n_in,
                              void* d_out, int out_size, void* d_ws, size_t ws_size,
                              hipStream_t stream) {
    const float* x    = (const float*)d_in[0];
    const int*   ei   = (const int*)  d_in[1];
    const int*   batch= (const int*)  d_in[2];
    const float* W1   = (const float*)d_in[3];
    const float* b1   = (const float*)d_in[4];
    const float* W2   = (const float*)d_in[5];
    const float* b2   = (const float*)d_in[6];
    const float* fW1  = (const float*)d_in[7];
    const float* fb1  = (const float*)d_in[8];
    const float* fW2  = (const float*)d_in[9];
    const float* fb2  = (const float*)d_in[10];
    const int* src = ei;
    const int* dst = ei + N_EDGES;
    float* out = (float*)d_out;

    char* ws = (char*)d_ws;
    // zero-init region: [deg | pool | cnt]
    int*   deg  = (int*)ws;                ws += (size_t)N_NODES * 4;
    float* pool = (float*)ws;              ws += (size_t)G_GRAPHS * HDIM * 4;
    int*   cnt  = (int*)ws;                ws += (size_t)G_GRAPHS * 4;
    size_t zero0_bytes = (size_t)N_NODES * 4 + (size_t)G_GRAPHS * HDIM * 4 + (size_t)G_GRAPHS * 4;
    float* dis  = (float*)ws;              ws += (size_t)N_NODES * 4;
    float* agg1 = (float*)ws;              ws += (size_t)N_NODES * 4;
    float* sorted_t = (float*)ws;          ws += HDIM * 4;
    int*   rankArr  = (int*)ws;            ws += HDIM * 4;
    float* hist = (float*)ws;              // [N][65][2]
    size_t hist_bytes = (size_t)N_NODES * NBUCK * 2 * 4;
    size_t need_new = (size_t)((char*)hist - (char*)d_ws) + hist_bytes;

    hipMemsetAsync(deg, 0, zero0_bytes, stream);
    k1_deg<<<(N_EDGES + 255) / 256, 256, 0, stream>>>(dst, deg);
    k2_dis<<<(N_NODES + 255) / 256, 256, 0, stream>>>(deg, x, dis, agg1);
    k3_agg1<<<(N_EDGES + 255) / 256, 256, 0, stream>>>(src, dst, dis, x, agg1);

    if (ws_size >= need_new) {
        hipMemsetAsync(hist, 0, hist_bytes, stream);
        kprep<<<1, HDIM, 0, stream>>>(W1, b1, sorted_t, rankArr);
        k5_bucket<<<(N_EDGES + 255) / 256, 256, 0, stream>>>(src, dst, dis, agg1, sorted_t, hist);
        knode<<<2048, 256, 0, stream>>>((const float2*)hist, rankArr, W1, b1, agg1, dis,
                                        W2, b2, batch, pool, cnt);
    } else {
        float* agg2 = (float*)hist;   // reuse tail region (25.6 MB)
        k4_agg2init<<<(N_NODES * HDIM + 255) / 256, 256, 0, stream>>>(agg1, dis, W1, b1, agg2);
        int k5_blocks = (int)(((long long)N_EDGES * HDIM + 255) / 256);
        k5_edge<<<k5_blocks, 256, 0, stream>>>(src, dst, dis, agg1, W1, b1, agg2);
        k6_pool<<<2048, 256, 0, stream>>>(agg2, W2, b2, batch, pool, cnt);
    }
    k7_mlp<<<G_GRAPHS, 64, 0, stream>>>(pool, cnt, fW1, fb1, fW2, fb2, out);
}

// Round 3
// 652.799 us; speedup vs baseline: 1.7579x; 1.2512x over previous
//
#include <hip/hip_runtime.h>

#define N_NODES 100000
#define N_EDGES 3200000
#define G_GRAPHS 512
#define HDIM 64
#define NBUCK 65   // worst-case buckets (64 distinct thresholds + 1)

// ---------------- kprep: distinct relu thresholds, ranks, flags (1 block, 64 thr)
__global__ void kprep(const float* __restrict__ W1, const float* __restrict__ b1,
                      float* __restrict__ dt, int* __restrict__ rank_d,
                      int* __restrict__ meta) {
    __shared__ float ts[HDIM], srt[HDIM];
    __shared__ int isnew[HDIM], bW[HDIM];
    int j = threadIdx.x;
    float w1 = W1[j], bb = b1[j];
    // w1==0 channels park at a shared sentinel (merges to <=1 wasted bucket; harmless)
    float tj = (w1 != 0.f) ? (-bb / w1) : -1e30f;
    ts[j] = tj;
    bW[j] = (bb != 0.f) ? 1 : 0;
    __syncthreads();
    int r = 0;
    for (int i = 0; i < HDIM; ++i) {
        float ti = ts[i];
        if (ti < tj || (ti == tj && i < j)) r++;    // stable rank
    }
    srt[r] = tj;
    __syncthreads();
    isnew[r] = (r == 0) || (srt[r] != srt[r - 1]);
    __syncthreads();
    int didx = 0;
    for (int q = 0; q <= r; ++q) didx += isnew[q];
    didx -= 1;                                      // distinct index of this value
    if (isnew[r]) dt[didx] = srt[r];
    rank_d[j] = didx;                               // #distinct thresholds < t_j
    if (j == 0) {
        int nd = 0, nw = 0;
        for (int q = 0; q < HDIM; ++q) { nd += isnew[q]; nw |= bW[q]; }
        meta[0] = nd;
        meta[1] = nw;
    }
}

// ---------------- kzero: meta-driven zeroing of all accumulators
__global__ void kzero(int* __restrict__ deg, float* __restrict__ q,
                      float* __restrict__ pool, int* __restrict__ cnt,
                      float* __restrict__ histA, float* __restrict__ histW,
                      const int* __restrict__ meta) {
    int nd1 = meta[0] + 1, needW = meta[1];
    size_t nh = (size_t)nd1 * N_NODES;
    size_t tid = (size_t)blockIdx.x * blockDim.x + threadIdx.x;
    size_t stride = (size_t)gridDim.x * blockDim.x;
    for (size_t i = tid; i < N_NODES; i += stride) { deg[i] = 0; q[i] = 0.f; }
    for (size_t i = tid; i < G_GRAPHS * HDIM; i += stride) pool[i] = 0.f;
    for (size_t i = tid; i < G_GRAPHS; i += stride) cnt[i] = 0;
    for (size_t i = tid; i < nh; i += stride) histA[i] = 0.f;
    if (needW) for (size_t i = tid; i < nh; i += stride) histW[i] = 0.f;
}

// ---------------- degree histogram
__global__ void k1_deg(const int* __restrict__ dst, int* __restrict__ deg) {
    int e = blockIdx.x * blockDim.x + threadIdx.x;
    if (e < N_EDGES) atomicAdd(&deg[dst[e]], 1);
}

// ---------------- dis = rsqrt(deg+1); u = dis*x
__global__ void k2_dis(const int* __restrict__ deg, const float* __restrict__ x,
                       float* __restrict__ dis, float* __restrict__ u) {
    int n = blockIdx.x * blockDim.x + threadIdx.x;
    if (n < N_NODES) {
        float d = rsqrtf((float)(deg[n] + 1));
        dis[n] = d;
        u[n] = d * x[n];
    }
}

// ---------------- layer-1: q[d] += u[s]   (dis[d] factored out)
__global__ void k3_q(const int* __restrict__ src, const int* __restrict__ dst,
                     const float* __restrict__ u, float* __restrict__ q) {
    int e = blockIdx.x * blockDim.x + threadIdx.x;
    if (e < N_EDGES) atomicAdd(&q[dst[e]], u[src[e]]);
}

// ---------------- finalize agg1; pack (agg1, dis) as float2
__global__ void k3b(const int* __restrict__ deg, const float* __restrict__ x,
                    const float* __restrict__ dis, const float* __restrict__ q,
                    float2* __restrict__ ad) {
    int n = blockIdx.x * blockDim.x + threadIdx.x;
    if (n < N_NODES) {
        float d = dis[n];
        float a = d * q[n] + x[n] / (float)(deg[n] + 1);
        ad[n] = make_float2(a, d);
    }
}

// ---------------- layer-2 edge scatter: 1-2 atomics/edge into (nd+1) compact buckets
__global__ void k5_bucket(const int* __restrict__ src, const int* __restrict__ dst,
                          const float2* __restrict__ ad, const float* __restrict__ dt,
                          const int* __restrict__ meta,
                          float* __restrict__ histA, float* __restrict__ histW) {
    __shared__ float dtS[HDIM];
    int nd = meta[0], needW = meta[1];
    if (threadIdx.x < nd) dtS[threadIdx.x] = dt[threadIdx.x];
    __syncthreads();
    int e = blockIdx.x * blockDim.x + threadIdx.x;
    if (e < N_EDGES) {
        int s = src[e], d = dst[e];
        float2 t = ad[s];                 // one 8B gather (L2-resident 800KB)
        float a = t.x;
        int k = 0;
        for (int i = 0; i < nd; ++i) k += (dtS[i] < a) ? 1 : 0;
        atomicAdd(&histA[(size_t)k * N_NODES + d], t.y * a);
        if (needW) atomicAdd(&histW[(size_t)k * N_NODES + d], t.y);
    }
}

// ---- fused node kernel: bucket scan -> agg2 -> @W2+b2 -> relu -> chunked pool
__global__ void knode(const float* __restrict__ histA, const float* __restrict__ histW,
                      const int* __restrict__ rank_d, const int* __restrict__ meta,
                      const float* __restrict__ W1, const float* __restrict__ b1,
                      const float2* __restrict__ ad,
                      const float* __restrict__ W2, const float* __restrict__ b2,
                      const int* __restrict__ batch,
                      float* __restrict__ pool, int* __restrict__ cnt) {
    __shared__ float w2s[HDIM * HDIM];               // 16 KB
    int tid = threadIdx.x;
    for (int i = tid; i < HDIM * HDIM; i += blockDim.x) w2s[i] = W2[i];
    __syncthreads();
    int nd = meta[0], needW = meta[1];
    int lane = tid & 63, wid = tid >> 6;
    float w1 = W1[lane], bb = b1[lane];
    int r = rank_d[lane];
    float bB2 = b2[lane];
    int nwaves = gridDim.x * (blockDim.x >> 6);
    int wave_g = blockIdx.x * (blockDim.x >> 6) + wid;
    int per = (N_NODES + nwaves - 1) / nwaves;
    int n0 = wave_g * per;
    int n1 = min(n0 + per, N_NODES);
    float accP = 0.f; int accC = 0; int gcur = -1;
    for (int n = n0; n < n1; ++n) {
        float PA = (lane <= nd) ? histA[(size_t)lane * N_NODES + n] : 0.f;
        float PW = (needW && lane <= nd) ? histW[(size_t)lane * N_NODES + n] : 0.f;
        float b64A = (nd == 64) ? histA[(size_t)64 * N_NODES + n] : 0.f;
        float b64W = (nd == 64 && needW) ? histW[(size_t)64 * N_NODES + n] : 0.f;
        #pragma unroll
        for (int off = 1; off < 64; off <<= 1) {     // inclusive scan over buckets
            float tA = __shfl_up(PA, off, 64);
            float tW = __shfl_up(PW, off, 64);
            if (lane >= off) { PA += tA; PW += tW; }
        }
        float TA = __shfl(PA, 63, 64) + b64A;
        float TW = __shfl(PW, 63, 64) + b64W;
        float sA = __shfl(PA, r, 64);                // prefix incl. bucket r  (a <= t_j side)
        float sW = __shfl(PW, r, 64);
        float2 adn = ad[n];
        float dn = adn.y;
        float nb;
        if (w1 > 0.f)      nb = w1 * (TA - sA) + bb * (TW - sW);
        else if (w1 < 0.f) nb = w1 * sA + bb * sW;
        else               nb = fmaxf(bb, 0.f) * TW;
        float agg2j = dn * nb + dn * dn * fmaxf(adn.x * w1 + bb, 0.f);
        float acc = bB2;                             // h2 = relu(agg2 @ W2 + b2)
        #pragma unroll
        for (int kk = 0; kk < HDIM; ++kk)
            acc += __shfl(agg2j, kk, 64) * w2s[kk * HDIM + lane];
        acc = fmaxf(acc, 0.f);
        int g = batch[n];                            // sorted -> long same-g runs
        if (g != gcur) {
            if (gcur >= 0) {
                atomicAdd(&pool[(size_t)gcur * HDIM + lane], accP);
                if (lane == 0) atomicAdd(&cnt[gcur], accC);
            }
            gcur = g; accP = 0.f; accC = 0;
        }
        accP += acc; accC++;
    }
    if (gcur >= 0) {
        atomicAdd(&pool[(size_t)gcur * HDIM + lane], accP);
        if (lane == 0) atomicAdd(&cnt[gcur], accC);
    }
}

// ---------------- final MLP per graph
__global__ void k7_mlp(const float* __restrict__ pool, const int* __restrict__ cnt,
                       const float* __restrict__ fW1, const float* __restrict__ fb1,
                       const float* __restrict__ fW2, const float* __restrict__ fb2,
                       float* __restrict__ out) {
    __shared__ float p[HDIM];
    __shared__ float tt[32];
    int g = blockIdx.x;
    int tid = threadIdx.x;
    float c = fmaxf((float)cnt[g], 1.f);
    p[tid] = pool[g * HDIM + tid] / c;
    __syncthreads();
    if (tid < 32) {
        float acc = fb1[tid];
        #pragma unroll
        for (int j = 0; j < HDIM; ++j) acc += p[j] * fW1[j * 32 + tid];
        tt[tid] = fmaxf(acc, 0.f);
    }
    __syncthreads();
    if (tid < 7) {
        float acc = fb2[tid];
        #pragma unroll
        for (int i = 0; i < 32; ++i) acc += tt[i] * fW2[i * 7 + tid];
        out[g * 7 + tid] = acc;
    }
}

// =================== fallback path (round-1 kernels, if ws too small) ===================
__global__ void kf2_dis(const int* __restrict__ deg, const float* __restrict__ x,
                        float* __restrict__ dis, float* __restrict__ agg1) {
    int n = blockIdx.x * blockDim.x + threadIdx.x;
    if (n < N_NODES) {
        float d = (float)(deg[n] + 1);
        dis[n] = rsqrtf(d);
        agg1[n] = x[n] / d;
    }
}
__global__ void kf3_agg1(const int* __restrict__ src, const int* __restrict__ dst,
                         const float* __restrict__ dis, const float* __restrict__ x,
                         float* __restrict__ agg1) {
    int e = blockIdx.x * blockDim.x + threadIdx.x;
    if (e < N_EDGES) {
        int s = src[e], d = dst[e];
        atomicAdd(&agg1[d], dis[s] * dis[d] * x[s]);
    }
}
__global__ void kf4_agg2init(const float* __restrict__ agg1, const float* __restrict__ dis,
                             const float* __restrict__ W1, const float* __restrict__ b1,
                             float* __restrict__ agg2) {
    int i = blockIdx.x * blockDim.x + threadIdx.x;
    if (i < N_NODES * HDIM) {
        int n = i >> 6, j = i & 63;
        float h = fmaxf(agg1[n] * W1[j] + b1[j], 0.f);
        float r = dis[n];
        agg2[i] = r * r * h;
    }
}
__global__ void kf5_edge(const int* __restrict__ src, const int* __restrict__ dst,
                         const float* __restrict__ dis, const float* __restrict__ agg1,
                         const float* __restrict__ W1, const float* __restrict__ b1,
                         float* __restrict__ agg2) {
    int t = blockIdx.x * blockDim.x + threadIdx.x;
    int e = t >> 6, j = t & 63;
    if (e < N_EDGES) {
        int s = src[e], d = dst[e];
        float w = dis[s] * dis[d];
        float h = fmaxf(agg1[s] * W1[j] + b1[j], 0.f);
        atomicAdd(&agg2[d * HDIM + j], w * h);
    }
}
__global__ void kf6_pool(const float* __restrict__ agg2, const float* __restrict__ W2,
                         const float* __restrict__ b2, const int* __restrict__ batch,
                         float* __restrict__ pool, int* __restrict__ cnt) {
    __shared__ float w2s[HDIM * HDIM];
    int tid = threadIdx.x;
    for (int i = tid; i < HDIM * HDIM; i += blockDim.x) w2s[i] = W2[i];
    __syncthreads();
    int lane = tid & 63, wid = tid >> 6;
    int nwaves = gridDim.x * 4;
    for (int n = blockIdx.x * 4 + wid; n < N_NODES; n += nwaves) {
        float av  = agg2[n * HDIM + lane];
        float acc = b2[lane];
        #pragma unroll
        for (int k = 0; k < HDIM; ++k)
            acc += __shfl(av, k, 64) * w2s[k * HDIM + lane];
        acc = fmaxf(acc, 0.f);
        int g = batch[n];
        atomicAdd(&pool[g * HDIM + lane], acc);
        if (lane == 0) atomicAdd(&cnt[g], 1);
    }
}

// ----------------------------------------------------------------------------
extern "C" void kernel_launch(void* const* d_in, const int* in_sizes, int n_in,
                              void* d_out, int out_size, void* d_ws, size_t ws_size,
                              hipStream_t stream) {
    const float* x    = (const float*)d_in[0];
    const int*   ei   = (const int*)  d_in[1];
    const int*   batch= (const int*)  d_in[2];
    const float* W1   = (const float*)d_in[3];
    const float* b1   = (const float*)d_in[4];
    const float* W2   = (const float*)d_in[5];
    const float* b2   = (const float*)d_in[6];
    const float* fW1  = (const float*)d_in[7];
    const float* fb1  = (const float*)d_in[8];
    const float* fW2  = (const float*)d_in[9];
    const float* fb2  = (const float*)d_in[10];
    const int* src = ei;
    const int* dst = ei + N_EDGES;
    float* out = (float*)d_out;

    char* ws = (char*)d_ws;
    int*    deg   = (int*)ws;    ws += (size_t)N_NODES * 4;
    float*  pool  = (float*)ws;  ws += (size_t)G_GRAPHS * HDIM * 4;
    int*    cnt   = (int*)ws;    ws += (size_t)G_GRAPHS * 4;
    float*  dis   = (float*)ws;  ws += (size_t)N_NODES * 4;
    float*  u     = (float*)ws;  ws += (size_t)N_NODES * 4;
    float*  q     = (float*)ws;  ws += (size_t)N_NODES * 4;
    float2* ad    = (float2*)ws; ws += (size_t)N_NODES * 8;
    float*  dt    = (float*)ws;  ws += HDIM * 4;
    int*    rankd = (int*)ws;    ws += HDIM * 4;
    int*    meta  = (int*)ws;    ws += 64;
    float*  histA = (float*)ws;  // [<=65][N]
    float*  histW = histA + (size_t)NBUCK * N_NODES;
    size_t need_new = (size_t)((char*)histA - (char*)d_ws)
                    + (size_t)NBUCK * N_NODES * 2 * 4;

    if (ws_size >= need_new) {
        kprep<<<1, HDIM, 0, stream>>>(W1, b1, dt, rankd, meta);
        kzero<<<2048, 256, 0, stream>>>(deg, q, pool, cnt, histA, histW, meta);
        k1_deg<<<(N_EDGES + 255) / 256, 256, 0, stream>>>(dst, deg);
        k2_dis<<<(N_NODES + 255) / 256, 256, 0, stream>>>(deg, x, dis, u);
        k3_q<<<(N_EDGES + 255) / 256, 256, 0, stream>>>(src, dst, u, q);
        k3b<<<(N_NODES + 255) / 256, 256, 0, stream>>>(deg, x, dis, q, ad);
        k5_bucket<<<(N_EDGES + 255) / 256, 256, 0, stream>>>(src, dst, ad, dt, meta, histA, histW);
        knode<<<1024, 256, 0, stream>>>(histA, histW, rankd, meta, W1, b1, ad,
                                        W2, b2, batch, pool, cnt);
        k7_mlp<<<G_GRAPHS, 64, 0, stream>>>(pool, cnt, fW1, fb1, fW2, fb2, out);
    } else {
        // round-1 path: agg1 in q, agg2 in hist region
        float* agg1 = q;
        float* agg2 = (float*)histA;
        size_t zero_bytes = (size_t)N_NODES * 4 + (size_t)G_GRAPHS * HDIM * 4 + (size_t)G_GRAPHS * 4;
        hipMemsetAsync(deg, 0, zero_bytes, stream);   // deg|pool|cnt contiguous
        k1_deg<<<(N_EDGES + 255) / 256, 256, 0, stream>>>(dst, deg);
        kf2_dis<<<(N_NODES + 255) / 256, 256, 0, stream>>>(deg, x, dis, agg1);
        kf3_agg1<<<(N_EDGES + 255) / 256, 256, 0, stream>>>(src, dst, dis, x, agg1);
        kf4_agg2init<<<(N_NODES * HDIM + 255) / 256, 256, 0, stream>>>(agg1, dis, W1, b1, agg2);
        int k5_blocks = (int)(((long long)N_EDGES * HDIM + 255) / 256);
        kf5_edge<<<k5_blocks, 256, 0, stream>>>(src, dst, dis, agg1, W1, b1, agg2);
        kf6_pool<<<2048, 256, 0, stream>>>(agg2, W2, b2, batch, pool, cnt);
        k7_mlp<<<G_GRAPHS, 64, 0, stream>>>(pool, cnt, fW1, fb1, fW2, fb2, out);
    }
}

// Round 4
// 528.490 us; speedup vs baseline: 2.1714x; 1.2352x over previous
//
#include <hip/hip_runtime.h>

#define N_NODES 100000
#define N_EDGES 3200000
#define G_GRAPHS 512
#define HDIM 64
#define NBUCK 65   // worst-case buckets (64 distinct thresholds + 1)

// ---------------- kprep: distinct relu thresholds, ranks, perm, flags (1 block, 64 thr)
__global__ void kprep(const float* __restrict__ W1, const float* __restrict__ b1,
                      float* __restrict__ dt, int* __restrict__ rank_d,
                      int* __restrict__ kperm, int* __restrict__ meta) {
    __shared__ float ts[HDIM], srt[HDIM];
    __shared__ int isnew[HDIM], bW[HDIM];
    int j = threadIdx.x;
    float w1 = W1[j], bb = b1[j];
    float tj = (w1 != 0.f) ? (-bb / w1) : -1e30f;   // sentinel for w1==0
    ts[j] = tj;
    bW[j] = (bb != 0.f) ? 1 : 0;
    __syncthreads();
    int r = 0;
    for (int i = 0; i < HDIM; ++i) {
        float ti = ts[i];
        if (ti < tj || (ti == tj && i < j)) r++;    // stable rank (unique 0..63)
    }
    srt[r] = tj;
    kperm[r] = j;                                   // channels sorted by threshold
    __syncthreads();
    isnew[r] = (r == 0) || (srt[r] != srt[r - 1]);
    __syncthreads();
    int didx = 0;
    for (int q = 0; q <= r; ++q) didx += isnew[q];
    didx -= 1;                                      // distinct index of this value
    if (isnew[r]) dt[didx] = srt[r];
    rank_d[j] = didx;
    if (j == 0) {
        int nd = 0, nw = 0;
        for (int q = 0; q < HDIM; ++q) { nd += isnew[q]; nw |= bW[q]; }
        meta[0] = nd;
        meta[1] = nw;
    }
}

// ---------------- kprep2: permuted W2 rows + per-rank channel params
__global__ void kprep2(const float* __restrict__ W1, const float* __restrict__ b1,
                       const int* __restrict__ kperm, const int* __restrict__ rank_d,
                       const float* __restrict__ W2,
                       float* __restrict__ w2p, float* __restrict__ pw1,
                       float* __restrict__ pb1, int* __restrict__ pdidx) {
    int i = blockIdx.x * blockDim.x + threadIdx.x;  // 4096
    if (i < HDIM * HDIM) {
        int r = i >> 6, j2 = i & 63;
        int j = kperm[r];
        w2p[i] = W2[j * HDIM + j2];
        if (j2 == 0) { pw1[r] = W1[j]; pb1[r] = b1[j]; pdidx[r] = rank_d[j]; }
    }
}

// ---------------- kzero: meta-driven zeroing of all accumulators
__global__ void kzero(int* __restrict__ deg, float* __restrict__ q,
                      float* __restrict__ pool, int* __restrict__ cnt,
                      float* __restrict__ histA, float* __restrict__ histW,
                      const int* __restrict__ meta) {
    int nd1 = meta[0] + 1, needW = meta[1];
    size_t nh = (size_t)nd1 * N_NODES;
    size_t tid = (size_t)blockIdx.x * blockDim.x + threadIdx.x;
    size_t stride = (size_t)gridDim.x * blockDim.x;
    for (size_t i = tid; i < N_NODES; i += stride) { deg[i] = 0; q[i] = 0.f; }
    for (size_t i = tid; i < G_GRAPHS * HDIM; i += stride) pool[i] = 0.f;
    for (size_t i = tid; i < G_GRAPHS; i += stride) cnt[i] = 0;
    for (size_t i = tid; i < nh; i += stride) histA[i] = 0.f;
    if (needW) for (size_t i = tid; i < nh; i += stride) histW[i] = 0.f;
}

// ---------------- degree histogram
__global__ void k1_deg(const int* __restrict__ dst, int* __restrict__ deg) {
    int e = blockIdx.x * blockDim.x + threadIdx.x;
    if (e < N_EDGES) atomicAdd(&deg[dst[e]], 1);
}

// ---------------- dis = rsqrt(deg+1); u = dis*x
__global__ void k2_dis(const int* __restrict__ deg, const float* __restrict__ x,
                       float* __restrict__ dis, float* __restrict__ u) {
    int n = blockIdx.x * blockDim.x + threadIdx.x;
    if (n < N_NODES) {
        float d = rsqrtf((float)(deg[n] + 1));
        dis[n] = d;
        u[n] = d * x[n];
    }
}

// ---------------- layer-1: q[d] += u[s]   (dis[d] factored out)
__global__ void k3_q(const int* __restrict__ src, const int* __restrict__ dst,
                     const float* __restrict__ u, float* __restrict__ q) {
    int e = blockIdx.x * blockDim.x + threadIdx.x;
    if (e < N_EDGES) atomicAdd(&q[dst[e]], u[src[e]]);
}

// ---------------- finalize agg1; pack (agg1, dis) as float2
__global__ void k3b(const int* __restrict__ deg, const float* __restrict__ x,
                    const float* __restrict__ dis, const float* __restrict__ q,
                    float2* __restrict__ ad) {
    int n = blockIdx.x * blockDim.x + threadIdx.x;
    if (n < N_NODES) {
        float d = dis[n];
        float a = d * q[n] + x[n] / (float)(deg[n] + 1);
        ad[n] = make_float2(a, d);
    }
}

// ---------------- layer-2 edge scatter: 1-2 atomics/edge into (nd+1) compact buckets
__global__ void k5_bucket(const int* __restrict__ src, const int* __restrict__ dst,
                          const float2* __restrict__ ad, const float* __restrict__ dt,
                          const int* __restrict__ meta,
                          float* __restrict__ histA, float* __restrict__ histW) {
    __shared__ float dtS[HDIM];
    int nd = meta[0], needW = meta[1];
    if (threadIdx.x < nd) dtS[threadIdx.x] = dt[threadIdx.x];
    __syncthreads();
    int e = blockIdx.x * blockDim.x + threadIdx.x;
    if (e < N_EDGES) {
        int s = src[e], d = dst[e];
        float2 t = ad[s];
        float a = t.x;
        int k = 0;
        for (int i = 0; i < nd; ++i) k += (dtS[i] < a) ? 1 : 0;
        atomicAdd(&histA[(size_t)k * N_NODES + d], t.y * a);
        if (needW) atomicAdd(&histW[(size_t)k * N_NODES + d], t.y);
    }
}

// ---- knode v2: lane = node. bucket prefix-walk -> areg[64] (rank order) ->
//      register matmul with pre-permuted W2 (uniform s_loads) -> LDS transpose pool.
__global__ __launch_bounds__(64) void knode(
        const float* __restrict__ histA, const float* __restrict__ histW,
        const int* __restrict__ meta,
        const float* __restrict__ pw1, const float* __restrict__ pb1,
        const int* __restrict__ pdidx, const float* __restrict__ w2p,
        const float2* __restrict__ ad, const float* __restrict__ b2,
        const int* __restrict__ batch,
        float* __restrict__ pool, int* __restrict__ cnt) {
    __shared__ float h2s[HDIM * 65];                 // [node][ch], stride 65: conflict-free both ways
    int lane = threadIdx.x;
    int n0 = blockIdx.x * 64;
    int nvalid = min(64, N_NODES - n0);
    int n = n0 + min(lane, nvalid - 1);              // clamp tail lanes (dup compute, unused)
    int nd = meta[0], needW = meta[1];
    float2 adn = ad[n];
    float a_n = adn.x, d_n = adn.y;

    float TA = 0.f, TW = 0.f;                        // totals over all buckets
    for (int k = 0; k <= nd; ++k) {
        TA += histA[(size_t)k * N_NODES + n];
        if (needW) TW += histW[(size_t)k * N_NODES + n];
    }

    float areg[HDIM];                                // agg2 in rank-sorted channel order
    float runA = 0.f, runW = 0.f;
    int cur = -1;
    #pragma unroll
    for (int jj = 0; jj < HDIM; ++jj) {
        int didx = pdidx[jj];                        // uniform, nondecreasing
        while (cur < didx) {
            ++cur;
            runA += histA[(size_t)cur * N_NODES + n];
            if (needW) runW += histW[(size_t)cur * N_NODES + n];
        }
        float w1 = pw1[jj], bb = pb1[jj];
        float nb;
        if (w1 > 0.f)      nb = w1 * (TA - runA) + bb * (TW - runW);
        else if (w1 < 0.f) nb = w1 * runA + bb * runW;
        else               nb = fmaxf(bb, 0.f) * TW;
        areg[jj] = d_n * nb + d_n * d_n * fmaxf(a_n * w1 + bb, 0.f);
    }

    // h2 = relu(agg2 @ W2 + b2): 4 chunks of 16 output channels, all-register
    #pragma unroll
    for (int c = 0; c < 4; ++c) {
        float acc[16];
        #pragma unroll
        for (int t = 0; t < 16; ++t) acc[t] = b2[c * 16 + t];
        #pragma unroll
        for (int jj = 0; jj < HDIM; ++jj) {
            float av = areg[jj];
            const float* wrow = w2p + jj * HDIM + c * 16;   // uniform -> s_load
            #pragma unroll
            for (int t = 0; t < 16; ++t) acc[t] += av * wrow[t];
        }
        #pragma unroll
        for (int t = 0; t < 16; ++t)
            h2s[lane * 65 + c * 16 + t] = fmaxf(acc[t], 0.f);
    }

    // pool phase: lane = channel; nodes sorted by graph -> batched run flush
    float accP = 0.f; int gcur = -1, runC = 0;
    for (int i = 0; i < nvalid; ++i) {
        int g = batch[n0 + i];                       // wave-uniform
        float v = h2s[i * 65 + lane];
        if (g != gcur) {
            if (gcur >= 0) {
                atomicAdd(&pool[(size_t)gcur * HDIM + lane], accP);
                if (lane == 0) atomicAdd(&cnt[gcur], runC);
            }
            gcur = g; accP = 0.f; runC = 0;
        }
        accP += v; ++runC;
    }
    if (gcur >= 0) {
        atomicAdd(&pool[(size_t)gcur * HDIM + lane], accP);
        if (lane == 0) atomicAdd(&cnt[gcur], runC);
    }
}

// ---------------- final MLP per graph
__global__ void k7_mlp(const float* __restrict__ pool, const int* __restrict__ cnt,
                       const float* __restrict__ fW1, const float* __restrict__ fb1,
                       const float* __restrict__ fW2, const float* __restrict__ fb2,
                       float* __restrict__ out) {
    __shared__ float p[HDIM];
    __shared__ float tt[32];
    int g = blockIdx.x;
    int tid = threadIdx.x;
    float c = fmaxf((float)cnt[g], 1.f);
    p[tid] = pool[g * HDIM + tid] / c;
    __syncthreads();
    if (tid < 32) {
        float acc = fb1[tid];
        #pragma unroll
        for (int j = 0; j < HDIM; ++j) acc += p[j] * fW1[j * 32 + tid];
        tt[tid] = fmaxf(acc, 0.f);
    }
    __syncthreads();
    if (tid < 7) {
        float acc = fb2[tid];
        #pragma unroll
        for (int i = 0; i < 32; ++i) acc += tt[i] * fW2[i * 7 + tid];
        out[g * 7 + tid] = acc;
    }
}

// =================== fallback path (round-1 kernels, if ws too small) ===================
__global__ void kf2_dis(const int* __restrict__ deg, const float* __restrict__ x,
                        float* __restrict__ dis, float* __restrict__ agg1) {
    int n = blockIdx.x * blockDim.x + threadIdx.x;
    if (n < N_NODES) {
        float d = (float)(deg[n] + 1);
        dis[n] = rsqrtf(d);
        agg1[n] = x[n] / d;
    }
}
__global__ void kf3_agg1(const int* __restrict__ src, const int* __restrict__ dst,
                         const float* __restrict__ dis, const float* __restrict__ x,
                         float* __restrict__ agg1) {
    int e = blockIdx.x * blockDim.x + threadIdx.x;
    if (e < N_EDGES) {
        int s = src[e], d = dst[e];
        atomicAdd(&agg1[d], dis[s] * dis[d] * x[s]);
    }
}
__global__ void kf4_agg2init(const float* __restrict__ agg1, const float* __restrict__ dis,
                             const float* __restrict__ W1, const float* __restrict__ b1,
                             float* __restrict__ agg2) {
    int i = blockIdx.x * blockDim.x + threadIdx.x;
    if (i < N_NODES * HDIM) {
        int n = i >> 6, j = i & 63;
        float h = fmaxf(agg1[n] * W1[j] + b1[j], 0.f);
        float r = dis[n];
        agg2[i] = r * r * h;
    }
}
__global__ void kf5_edge(const int* __restrict__ src, const int* __restrict__ dst,
                         const float* __restrict__ dis, const float* __restrict__ agg1,
                         const float* __restrict__ W1, const float* __restrict__ b1,
                         float* __restrict__ agg2) {
    int t = blockIdx.x * blockDim.x + threadIdx.x;
    int e = t >> 6, j = t & 63;
    if (e < N_EDGES) {
        int s = src[e], d = dst[e];
        float w = dis[s] * dis[d];
        float h = fmaxf(agg1[s] * W1[j] + b1[j], 0.f);
        atomicAdd(&agg2[d * HDIM + j], w * h);
    }
}
__global__ void kf6_pool(const float* __restrict__ agg2, const float* __restrict__ W2,
                         const float* __restrict__ b2, const int* __restrict__ batch,
                         float* __restrict__ pool, int* __restrict__ cnt) {
    __shared__ float w2s[HDIM * HDIM];
    int tid = threadIdx.x;
    for (int i = tid; i < HDIM * HDIM; i += blockDim.x) w2s[i] = W2[i];
    __syncthreads();
    int lane = tid & 63, wid = tid >> 6;
    int nwaves = gridDim.x * 4;
    for (int n = blockIdx.x * 4 + wid; n < N_NODES; n += nwaves) {
        float av  = agg2[n * HDIM + lane];
        float acc = b2[lane];
        #pragma unroll
        for (int k = 0; k < HDIM; ++k)
            acc += __shfl(av, k, 64) * w2s[k * HDIM + lane];
        acc = fmaxf(acc, 0.f);
        int g = batch[n];
        atomicAdd(&pool[g * HDIM + lane], acc);
        if (lane == 0) atomicAdd(&cnt[g], 1);
    }
}

// ----------------------------------------------------------------------------
extern "C" void kernel_launch(void* const* d_in, const int* in_sizes, int n_in,
                              void* d_out, int out_size, void* d_ws, size_t ws_size,
                              hipStream_t stream) {
    const float* x    = (const float*)d_in[0];
    const int*   ei   = (const int*)  d_in[1];
    const int*   batch= (const int*)  d_in[2];
    const float* W1   = (const float*)d_in[3];
    const float* b1   = (const float*)d_in[4];
    const float* W2   = (const float*)d_in[5];
    const float* b2   = (const float*)d_in[6];
    const float* fW1  = (const float*)d_in[7];
    const float* fb1  = (const float*)d_in[8];
    const float* fW2  = (const float*)d_in[9];
    const float* fb2  = (const float*)d_in[10];
    const int* src = ei;
    const int* dst = ei + N_EDGES;
    float* out = (float*)d_out;

    char* ws = (char*)d_ws;
    int*    deg   = (int*)ws;    ws += (size_t)N_NODES * 4;
    float*  pool  = (float*)ws;  ws += (size_t)G_GRAPHS * HDIM * 4;
    int*    cnt   = (int*)ws;    ws += (size_t)G_GRAPHS * 4;
    float*  dis   = (float*)ws;  ws += (size_t)N_NODES * 4;
    float*  u     = (float*)ws;  ws += (size_t)N_NODES * 4;
    float*  q     = (float*)ws;  ws += (size_t)N_NODES * 4;
    float2* ad    = (float2*)ws; ws += (size_t)N_NODES * 8;
    float*  dt    = (float*)ws;  ws += HDIM * 4;
    int*    rankd = (int*)ws;    ws += HDIM * 4;
    int*    kperm = (int*)ws;    ws += HDIM * 4;
    int*    meta  = (int*)ws;    ws += 64;
    float*  pw1   = (float*)ws;  ws += HDIM * 4;
    float*  pb1   = (float*)ws;  ws += HDIM * 4;
    int*    pdidx = (int*)ws;    ws += HDIM * 4;
    float*  w2p   = (float*)ws;  ws += HDIM * HDIM * 4;
    float*  histA = (float*)ws;  // [<=65][N]
    float*  histW = histA + (size_t)NBUCK * N_NODES;
    size_t need_new = (size_t)((char*)histA - (char*)d_ws)
                    + (size_t)NBUCK * N_NODES * 2 * 4;

    if (ws_size >= need_new) {
        kprep<<<1, HDIM, 0, stream>>>(W1, b1, dt, rankd, kperm, meta);
        kprep2<<<16, 256, 0, stream>>>(W1, b1, kperm, rankd, W2, w2p, pw1, pb1, pdidx);
        kzero<<<2048, 256, 0, stream>>>(deg, q, pool, cnt, histA, histW, meta);
        k1_deg<<<(N_EDGES + 255) / 256, 256, 0, stream>>>(dst, deg);
        k2_dis<<<(N_NODES + 255) / 256, 256, 0, stream>>>(deg, x, dis, u);
        k3_q<<<(N_EDGES + 255) / 256, 256, 0, stream>>>(src, dst, u, q);
        k3b<<<(N_NODES + 255) / 256, 256, 0, stream>>>(deg, x, dis, q, ad);
        k5_bucket<<<(N_EDGES + 255) / 256, 256, 0, stream>>>(src, dst, ad, dt, meta, histA, histW);
        knode<<<(N_NODES + 63) / 64, 64, 0, stream>>>(histA, histW, meta, pw1, pb1, pdidx,
                                                      w2p, ad, b2, batch, pool, cnt);
        k7_mlp<<<G_GRAPHS, 64, 0, stream>>>(pool, cnt, fW1, fb1, fW2, fb2, out);
    } else {
        // round-1 path: agg1 in q, agg2 in hist region
        float* agg1 = q;
        float* agg2 = (float*)histA;
        size_t zero_bytes = (size_t)N_NODES * 4 + (size_t)G_GRAPHS * HDIM * 4 + (size_t)G_GRAPHS * 4;
        hipMemsetAsync(deg, 0, zero_bytes, stream);   // deg|pool|cnt contiguous
        k1_deg<<<(N_EDGES + 255) / 256, 256, 0, stream>>>(dst, deg);
        kf2_dis<<<(N_NODES + 255) / 256, 256, 0, stream>>>(deg, x, dis, agg1);
        kf3_agg1<<<(N_EDGES + 255) / 256, 256, 0, stream>>>(src, dst, dis, x, agg1);
        kf4_agg2init<<<(N_NODES * HDIM + 255) / 256, 256, 0, stream>>>(agg1, dis, W1, b1, agg2);
        int k5_blocks = (int)(((long long)N_EDGES * HDIM + 255) / 256);
        kf5_edge<<<k5_blocks, 256, 0, stream>>>(src, dst, dis, agg1, W1, b1, agg2);
        kf6_pool<<<2048, 256, 0, stream>>>(agg2, W2, b2, batch, pool, cnt);
        k7_mlp<<<G_GRAPHS, 64, 0, stream>>>(pool, cnt, fW1, fb1, fW2, fb2, out);
    }
}

// Round 5
// 427.073 us; speedup vs baseline: 2.6871x; 1.2375x over previous
//
#include <hip/hip_runtime.h>

#define N_NODES 100000
#define N_EDGES 3200000
#define G_GRAPHS 512
#define HDIM 64
#define CAP 96        // per-node CSR capacity (mean deg 32, ~11 sigma margin)
#define OVCAP 65536   // overflow side-list capacity

// ---------------- kprep: distinct relu thresholds, ranks, perm, flags (1 block, 64 thr)
__global__ void kprep(const float* __restrict__ W1, const float* __restrict__ b1,
                      float* __restrict__ dt, int* __restrict__ rank_d,
                      int* __restrict__ kperm, int* __restrict__ meta) {
    __shared__ float ts[HDIM], srt[HDIM];
    __shared__ int isnew[HDIM], bW[HDIM];
    int j = threadIdx.x;
    float w1 = W1[j], bb = b1[j];
    float tj = (w1 != 0.f) ? (-bb / w1) : -1e30f;   // sentinel for w1==0
    ts[j] = tj;
    bW[j] = (bb != 0.f) ? 1 : 0;
    __syncthreads();
    int r = 0;
    for (int i = 0; i < HDIM; ++i) {
        float ti = ts[i];
        if (ti < tj || (ti == tj && i < j)) r++;    // stable rank (unique 0..63)
    }
    srt[r] = tj;
    kperm[r] = j;                                   // channels sorted by threshold
    __syncthreads();
    isnew[r] = (r == 0) || (srt[r] != srt[r - 1]);
    __syncthreads();
    int didx = 0;
    for (int q = 0; q <= r; ++q) didx += isnew[q];
    didx -= 1;                                      // distinct index of this value
    if (isnew[r]) dt[didx] = srt[r];
    rank_d[j] = didx;
    if (j == 0) {
        int nd = 0, nw = 0;
        for (int q = 0; q < HDIM; ++q) { nd += isnew[q]; nw |= bW[q]; }
        meta[0] = nd;
        meta[1] = nw;
    }
}

// ---------------- kprep2: permuted W2 rows + per-rank channel params
__global__ void kprep2(const float* __restrict__ W1, const float* __restrict__ b1,
                       const int* __restrict__ kperm, const int* __restrict__ rank_d,
                       const float* __restrict__ W2,
                       float* __restrict__ w2p, float* __restrict__ pw1,
                       float* __restrict__ pb1, int* __restrict__ pdidx) {
    int i = blockIdx.x * blockDim.x + threadIdx.x;  // 4096
    if (i < HDIM * HDIM) {
        int r = i >> 6, j2 = i & 63;
        int j = kperm[r];
        w2p[i] = W2[j * HDIM + j2];
        if (j2 == 0) { pw1[r] = W1[j]; pb1[r] = b1[j]; pdidx[r] = rank_d[j]; }
    }
}

// ---------------- kA: degree count + fixed-capacity CSR build (THE scattered pass)
__global__ void kA(const int* __restrict__ src, const int* __restrict__ dst,
                   int* __restrict__ deg, int* __restrict__ csrc,
                   int* __restrict__ ovcnt, int2* __restrict__ ovlist) {
    int e = blockIdx.x * blockDim.x + threadIdx.x;
    if (e < N_EDGES) {
        int s = src[e], d = dst[e];
        int slot = atomicAdd(&deg[d], 1);
        if (slot < CAP) csrc[(size_t)d * CAP + slot] = s;
        else {
            int i = atomicAdd(ovcnt, 1);
            if (i < OVCAP) ovlist[i] = make_int2(s, d);
        }
    }
}

// ---------------- dis = rsqrt(deg+1); u = dis*x
__global__ void k2_dis(const int* __restrict__ deg, const float* __restrict__ x,
                       float* __restrict__ dis, float* __restrict__ u) {
    int n = blockIdx.x * blockDim.x + threadIdx.x;
    if (n < N_NODES) {
        float d = rsqrtf((float)(deg[n] + 1));
        dis[n] = d;
        u[n] = d * x[n];
    }
}

// ---------------- kq: layer-1 gather-reduce over CSR; finalize (agg1, dis) pack
__global__ void kq(const int* __restrict__ deg, const int* __restrict__ csrc,
                   const float* __restrict__ u, const float* __restrict__ x,
                   const float* __restrict__ dis,
                   const int* __restrict__ ovcnt, const int2* __restrict__ ovlist,
                   float2* __restrict__ ad) {
    int n = blockIdx.x * blockDim.x + threadIdx.x;
    if (n >= N_NODES) return;
    int dg = deg[n];
    int m = min(dg, CAP);
    const int* p = &csrc[(size_t)n * CAP];
    float sum = 0.f;
    for (int i = 0; i < m; ++i) sum += u[p[i]];     // random 4B gathers, L2-resident
    int oc = min(*ovcnt, OVCAP);
    for (int i = 0; i < oc; ++i) {                  // oc == 0 in practice
        int2 od = ovlist[i];
        if (od.y == n) sum += u[od.x];
    }
    float dn = dis[n];
    ad[n] = make_float2(dn * sum + x[n] / (float)(dg + 1), dn);
}

// ---- knode: CSR walk -> bucket sums in regs -> agg2 -> @W2+b2 -> relu -> pool
__global__ __launch_bounds__(64) void knode(
        const int* __restrict__ deg, const int* __restrict__ csrc,
        const float2* __restrict__ ad,
        const int* __restrict__ ovcnt, const int2* __restrict__ ovlist,
        const int* __restrict__ meta, const float* __restrict__ dt,
        const float* __restrict__ pw1, const float* __restrict__ pb1,
        const int* __restrict__ pdidx, const float* __restrict__ w2p,
        const float* __restrict__ b2, const int* __restrict__ batch,
        float* __restrict__ pool, int* __restrict__ cnt) {
    __shared__ float h2s[HDIM * 65];                 // [node][ch], stride 65
    int lane = threadIdx.x;
    int n0 = blockIdx.x * 64;
    int nvalid = min(64, N_NODES - n0);
    int n = n0 + min(lane, nvalid - 1);              // clamp tail (dup rows unused)
    int nd = meta[0];
    float2 adn = ad[n];
    float a_n = adn.x, d_n = adn.y;
    int dg = deg[n];
    int m = min(dg, CAP);
    const int* p = &csrc[(size_t)n * CAP];
    int oc = min(*ovcnt, OVCAP);

    float areg[HDIM];                                // agg2 in rank-sorted order

    if (nd <= 4) {
        // bucket path: <=5 accumulators, compare-select (no indexed arrays)
        float t0 = (nd > 0) ? dt[0] : 3.4e38f;
        float t1 = (nd > 1) ? dt[1] : 3.4e38f;
        float t2 = (nd > 2) ? dt[2] : 3.4e38f;
        float t3 = (nd > 3) ? dt[3] : 3.4e38f;
        float bA0=0,bA1=0,bA2=0,bA3=0,bA4=0;
        float bW0=0,bW1=0,bW2=0,bW3=0,bW4=0;
        for (int i = 0; i < m; ++i) {
            float2 t = ad[p[i]];                     // random 8B gather, L2-resident
            float a = t.x, w = t.y, v = w * a;
            int k = (int)(t0 < a) + (int)(t1 < a) + (int)(t2 < a) + (int)(t3 < a);
            bA0 += (k==0)?v:0.f; bW0 += (k==0)?w:0.f;
            bA1 += (k==1)?v:0.f; bW1 += (k==1)?w:0.f;
            bA2 += (k==2)?v:0.f; bW2 += (k==2)?w:0.f;
            bA3 += (k==3)?v:0.f; bW3 += (k==3)?w:0.f;
            bA4 += (k==4)?v:0.f; bW4 += (k==4)?w:0.f;
        }
        for (int i = 0; i < oc; ++i) {               // exact overflow handling
            int2 od = ovlist[i];
            if (od.y == n) {
                float2 t = ad[od.x];
                float a = t.x, w = t.y, v = w * a;
                int k = (int)(t0 < a) + (int)(t1 < a) + (int)(t2 < a) + (int)(t3 < a);
                bA0 += (k==0)?v:0.f; bW0 += (k==0)?w:0.f;
                bA1 += (k==1)?v:0.f; bW1 += (k==1)?w:0.f;
                bA2 += (k==2)?v:0.f; bW2 += (k==2)?w:0.f;
                bA3 += (k==3)?v:0.f; bW3 += (k==3)?w:0.f;
                bA4 += (k==4)?v:0.f; bW4 += (k==4)?w:0.f;
            }
        }
        float pA0=bA0, pA1=pA0+bA1, pA2=pA1+bA2, pA3=pA2+bA3, pA4=pA3+bA4;
        float pW0=bW0, pW1=pW0+bW1, pW2=pW1+bW2, pW3=pW2+bW3, pW4=pW3+bW4;
        float TA=pA4, TW=pW4;
        #pragma unroll
        for (int jj = 0; jj < HDIM; ++jj) {
            int didx = pdidx[jj];                    // uniform
            float runA = (didx==0)?pA0:(didx==1)?pA1:(didx==2)?pA2:(didx==3)?pA3:pA4;
            float runW = (didx==0)?pW0:(didx==1)?pW1:(didx==2)?pW2:(didx==3)?pW3:pW4;
            float w1 = pw1[jj], bb = pb1[jj];
            float nb;
            if (w1 > 0.f)      nb = w1*(TA-runA) + bb*(TW-runW);
            else if (w1 < 0.f) nb = w1*runA + bb*runW;
            else               nb = fmaxf(bb, 0.f)*TW;
            areg[jj] = d_n*nb + d_n*d_n*fmaxf(a_n*w1 + bb, 0.f);
        }
    } else {
        // general path: direct 64-channel evaluation (rare; any W1/b1)
        #pragma unroll
        for (int jj = 0; jj < HDIM; ++jj) areg[jj] = 0.f;
        for (int i = 0; i < m; ++i) {
            float2 t = ad[p[i]];
            float a = t.x, w = t.y;
            #pragma unroll
            for (int jj = 0; jj < HDIM; ++jj)
                areg[jj] += w * fmaxf(a*pw1[jj] + pb1[jj], 0.f);
        }
        for (int i = 0; i < oc; ++i) {
            int2 od = ovlist[i];
            if (od.y == n) {
                float2 t = ad[od.x];
                #pragma unroll
                for (int jj = 0; jj < HDIM; ++jj)
                    areg[jj] += t.y * fmaxf(t.x*pw1[jj] + pb1[jj], 0.f);
            }
        }
        #pragma unroll
        for (int jj = 0; jj < HDIM; ++jj)
            areg[jj] = d_n*areg[jj] + d_n*d_n*fmaxf(a_n*pw1[jj] + pb1[jj], 0.f);
    }

    // h2 = relu(agg2 @ W2 + b2): 4 chunks of 16, all-register, uniform W rows
    #pragma unroll
    for (int c = 0; c < 4; ++c) {
        float acc[16];
        #pragma unroll
        for (int t = 0; t < 16; ++t) acc[t] = b2[c * 16 + t];
        #pragma unroll
        for (int jj = 0; jj < HDIM; ++jj) {
            float av = areg[jj];
            const float* wrow = w2p + jj * HDIM + c * 16;
            #pragma unroll
            for (int t = 0; t < 16; ++t) acc[t] += av * wrow[t];
        }
        #pragma unroll
        for (int t = 0; t < 16; ++t)
            h2s[lane * 65 + c * 16 + t] = fmaxf(acc[t], 0.f);
    }

    // pool phase: lane = channel; nodes sorted by graph -> batched run flush
    float accP = 0.f; int gcur = -1, runC = 0;
    for (int i = 0; i < nvalid; ++i) {
        int g = batch[n0 + i];                       // wave-uniform
        float v = h2s[i * 65 + lane];
        if (g != gcur) {
            if (gcur >= 0) {
                atomicAdd(&pool[(size_t)gcur * HDIM + lane], accP);
                if (lane == 0) atomicAdd(&cnt[gcur], runC);
            }
            gcur = g; accP = 0.f; runC = 0;
        }
        accP += v; ++runC;
    }
    if (gcur >= 0) {
        atomicAdd(&pool[(size_t)gcur * HDIM + lane], accP);
        if (lane == 0) atomicAdd(&cnt[gcur], runC);
    }
}

// ---------------- final MLP per graph
__global__ void k7_mlp(const float* __restrict__ pool, const int* __restrict__ cnt,
                       const float* __restrict__ fW1, const float* __restrict__ fb1,
                       const float* __restrict__ fW2, const float* __restrict__ fb2,
                       float* __restrict__ out) {
    __shared__ float p[HDIM];
    __shared__ float tt[32];
    int g = blockIdx.x;
    int tid = threadIdx.x;
    float c = fmaxf((float)cnt[g], 1.f);
    p[tid] = pool[g * HDIM + tid] / c;
    __syncthreads();
    if (tid < 32) {
        float acc = fb1[tid];
        #pragma unroll
        for (int j = 0; j < HDIM; ++j) acc += p[j] * fW1[j * 32 + tid];
        tt[tid] = fmaxf(acc, 0.f);
    }
    __syncthreads();
    if (tid < 7) {
        float acc = fb2[tid];
        #pragma unroll
        for (int i = 0; i < 32; ++i) acc += tt[i] * fW2[i * 7 + tid];
        out[g * 7 + tid] = acc;
    }
}

// =================== fallback path (round-1 kernels, if ws too small) ===================
__global__ void kf2_dis(const int* __restrict__ deg, const float* __restrict__ x,
                        float* __restrict__ dis, float* __restrict__ agg1) {
    int n = blockIdx.x * blockDim.x + threadIdx.x;
    if (n < N_NODES) {
        float d = (float)(deg[n] + 1);
        dis[n] = rsqrtf(d);
        agg1[n] = x[n] / d;
    }
}
__global__ void kf1_deg(const int* __restrict__ dst, int* __restrict__ deg) {
    int e = blockIdx.x * blockDim.x + threadIdx.x;
    if (e < N_EDGES) atomicAdd(&deg[dst[e]], 1);
}
__global__ void kf3_agg1(const int* __restrict__ src, const int* __restrict__ dst,
                         const float* __restrict__ dis, const float* __restrict__ x,
                         float* __restrict__ agg1) {
    int e = blockIdx.x * blockDim.x + threadIdx.x;
    if (e < N_EDGES) {
        int s = src[e], d = dst[e];
        atomicAdd(&agg1[d], dis[s] * dis[d] * x[s]);
    }
}
__global__ void kf4_agg2init(const float* __restrict__ agg1, const float* __restrict__ dis,
                             const float* __restrict__ W1, const float* __restrict__ b1,
                             float* __restrict__ agg2) {
    int i = blockIdx.x * blockDim.x + threadIdx.x;
    if (i < N_NODES * HDIM) {
        int n = i >> 6, j = i & 63;
        float h = fmaxf(agg1[n] * W1[j] + b1[j], 0.f);
        float r = dis[n];
        agg2[i] = r * r * h;
    }
}
__global__ void kf5_edge(const int* __restrict__ src, const int* __restrict__ dst,
                         const float* __restrict__ dis, const float* __restrict__ agg1,
                         const float* __restrict__ W1, const float* __restrict__ b1,
                         float* __restrict__ agg2) {
    int t = blockIdx.x * blockDim.x + threadIdx.x;
    int e = t >> 6, j = t & 63;
    if (e < N_EDGES) {
        int s = src[e], d = dst[e];
        float w = dis[s] * dis[d];
        float h = fmaxf(agg1[s] * W1[j] + b1[j], 0.f);
        atomicAdd(&agg2[d * HDIM + j], w * h);
    }
}
__global__ void kf6_pool(const float* __restrict__ agg2, const float* __restrict__ W2,
                         const float* __restrict__ b2, const int* __restrict__ batch,
                         float* __restrict__ pool, int* __restrict__ cnt) {
    __shared__ float w2s[HDIM * HDIM];
    int tid = threadIdx.x;
    for (int i = tid; i < HDIM * HDIM; i += blockDim.x) w2s[i] = W2[i];
    __syncthreads();
    int lane = tid & 63, wid = tid >> 6;
    int nwaves = gridDim.x * 4;
    for (int n = blockIdx.x * 4 + wid; n < N_NODES; n += nwaves) {
        float av  = agg2[n * HDIM + lane];
        float acc = b2[lane];
        #pragma unroll
        for (int k = 0; k < HDIM; ++k)
            acc += __shfl(av, k, 64) * w2s[k * HDIM + lane];
        acc = fmaxf(acc, 0.f);
        int g = batch[n];
        atomicAdd(&pool[g * HDIM + lane], acc);
        if (lane == 0) atomicAdd(&cnt[g], 1);
    }
}

// ----------------------------------------------------------------------------
extern "C" void kernel_launch(void* const* d_in, const int* in_sizes, int n_in,
                              void* d_out, int out_size, void* d_ws, size_t ws_size,
                              hipStream_t stream) {
    const float* x    = (const float*)d_in[0];
    const int*   ei   = (const int*)  d_in[1];
    const int*   batch= (const int*)  d_in[2];
    const float* W1   = (const float*)d_in[3];
    const float* b1   = (const float*)d_in[4];
    const float* W2   = (const float*)d_in[5];
    const float* b2   = (const float*)d_in[6];
    const float* fW1  = (const float*)d_in[7];
    const float* fb1  = (const float*)d_in[8];
    const float* fW2  = (const float*)d_in[9];
    const float* fb2  = (const float*)d_in[10];
    const int* src = ei;
    const int* dst = ei + N_EDGES;
    float* out = (float*)d_out;

    // workspace layout (256B-aligned regions)
    size_t off = 0;
    auto take = [&](size_t bytes) { size_t o = off; off = (off + bytes + 255) & ~(size_t)255; return o; };
    char* base = (char*)d_ws;
    // zero block: [deg | pool | cnt | ovcnt] contiguous
    int*    deg   = (int*)   (base + take((size_t)N_NODES * 4));
    float*  pool  = (float*) (base + take((size_t)G_GRAPHS * HDIM * 4));
    int*    cnt   = (int*)   (base + take((size_t)G_GRAPHS * 4));
    int*    ovcnt = (int*)   (base + take(4));
    size_t zero_end = off;
    float*  dis   = (float*) (base + take((size_t)N_NODES * 4));
    float*  u     = (float*) (base + take((size_t)N_NODES * 4));
    float2* ad    = (float2*)(base + take((size_t)N_NODES * 8));
    float*  dt    = (float*) (base + take(HDIM * 4));
    int*    rankd = (int*)   (base + take(HDIM * 4));
    int*    kperm = (int*)   (base + take(HDIM * 4));
    int*    meta  = (int*)   (base + take(64));
    float*  pw1   = (float*) (base + take(HDIM * 4));
    float*  pb1   = (float*) (base + take(HDIM * 4));
    int*    pdidx = (int*)   (base + take(HDIM * 4));
    float*  w2p   = (float*) (base + take(HDIM * HDIM * 4));
    int2*   ovlist= (int2*)  (base + take((size_t)OVCAP * 8));
    size_t csrc_off = off;
    int*    csrc  = (int*)   (base + take((size_t)N_NODES * CAP * 4));
    size_t need_fast = off;

    if (ws_size >= need_fast) {
        hipMemsetAsync(deg, 0, zero_end, stream);
        kprep <<<1, HDIM, 0, stream>>>(W1, b1, dt, rankd, kperm, meta);
        kprep2<<<16, 256, 0, stream>>>(W1, b1, kperm, rankd, W2, w2p, pw1, pb1, pdidx);
        kA    <<<(N_EDGES + 255) / 256, 256, 0, stream>>>(src, dst, deg, csrc, ovcnt, ovlist);
        k2_dis<<<(N_NODES + 255) / 256, 256, 0, stream>>>(deg, x, dis, u);
        kq    <<<(N_NODES + 255) / 256, 256, 0, stream>>>(deg, csrc, u, x, dis, ovcnt, ovlist, ad);
        knode <<<(N_NODES + 63) / 64, 64, 0, stream>>>(deg, csrc, ad, ovcnt, ovlist, meta, dt,
                                                       pw1, pb1, pdidx, w2p, b2, batch, pool, cnt);
        k7_mlp<<<G_GRAPHS, 64, 0, stream>>>(pool, cnt, fW1, fb1, fW2, fb2, out);
    } else {
        // round-1 path: agg1 in u, agg2 in csrc region
        float* agg1 = u;
        float* agg2 = (float*)(base + csrc_off);
        hipMemsetAsync(deg, 0, zero_end, stream);
        kf1_deg<<<(N_EDGES + 255) / 256, 256, 0, stream>>>(dst, deg);
        kf2_dis<<<(N_NODES + 255) / 256, 256, 0, stream>>>(deg, x, dis, agg1);
        kf3_agg1<<<(N_EDGES + 255) / 256, 256, 0, stream>>>(src, dst, dis, x, agg1);
        kf4_agg2init<<<(N_NODES * HDIM + 255) / 256, 256, 0, stream>>>(agg1, dis, W1, b1, agg2);
        int k5_blocks = (int)(((long long)N_EDGES * HDIM + 255) / 256);
        kf5_edge<<<k5_blocks, 256, 0, stream>>>(src, dst, dis, agg1, W1, b1, agg2);
        kf6_pool<<<2048, 256, 0, stream>>>(agg2, W2, b2, batch, pool, cnt);
        k7_mlp<<<G_GRAPHS, 64, 0, stream>>>(pool, cnt, fW1, fb1, fW2, fb2, out);
    }
}

// Round 6
// 172.578 us; speedup vs baseline: 6.6496x; 2.4747x over previous
//
#include <hip/hip_runtime.h>

#define N_NODES 100000
#define N_EDGES 3200000
#define G_GRAPHS 512
#define HDIM 64
#define BSH 7                  // 128 nodes per bucket
#define BNODES 128
#define NBK ((N_NODES + BNODES - 1) / BNODES)   // 782
#define CAPB 6144              // slots/bucket: mean 4096, +32 sigma
#define OVCAP 65536
#define EPW 8192               // edges per workgroup in kB

// ---------------- kprep: distinct relu thresholds, ranks, perm, flags
__global__ void kprep(const float* __restrict__ W1, const float* __restrict__ b1,
                      float* __restrict__ dt, int* __restrict__ rank_d,
                      int* __restrict__ kperm, int* __restrict__ meta) {
    __shared__ float ts[HDIM], srt[HDIM];
    __shared__ int isnew[HDIM], bW[HDIM];
    int j = threadIdx.x;
    float w1 = W1[j], bb = b1[j];
    float tj = (w1 != 0.f) ? (-bb / w1) : -1e30f;
    ts[j] = tj;
    bW[j] = (bb != 0.f) ? 1 : 0;
    __syncthreads();
    int r = 0;
    for (int i = 0; i < HDIM; ++i) {
        float ti = ts[i];
        if (ti < tj || (ti == tj && i < j)) r++;
    }
    srt[r] = tj;
    kperm[r] = j;
    __syncthreads();
    isnew[r] = (r == 0) || (srt[r] != srt[r - 1]);
    __syncthreads();
    int didx = 0;
    for (int q = 0; q <= r; ++q) didx += isnew[q];
    didx -= 1;
    if (isnew[r]) dt[didx] = srt[r];
    rank_d[j] = didx;
    if (j == 0) {
        int nd = 0, nw = 0;
        for (int q = 0; q < HDIM; ++q) { nd += isnew[q]; nw |= bW[q]; }
        meta[0] = nd;
        meta[1] = nw;
    }
}

// ---------------- kprep2: permuted W2 rows + per-rank channel params
__global__ void kprep2(const float* __restrict__ W1, const float* __restrict__ b1,
                       const int* __restrict__ kperm, const int* __restrict__ rank_d,
                       const float* __restrict__ W2,
                       float* __restrict__ w2p, float* __restrict__ pw1,
                       float* __restrict__ pb1, int* __restrict__ pdidx) {
    int i = blockIdx.x * blockDim.x + threadIdx.x;
    if (i < HDIM * HDIM) {
        int r = i >> 6, j2 = i & 63;
        int j = kperm[r];
        w2p[i] = W2[j * HDIM + j2];
        if (j2 == 0) { pw1[r] = W1[j]; pb1[r] = b1[j]; pdidx[r] = rank_d[j]; }
    }
}

// ---------------- kzero: small accumulators + bucket bump pointers
__global__ void kzero(float* __restrict__ pool, int* __restrict__ cnt,
                      int* __restrict__ ovcnt, int* __restrict__ bcur) {
    int i = blockIdx.x * blockDim.x + threadIdx.x;
    if (i < G_GRAPHS * HDIM) pool[i] = 0.f;
    if (i < G_GRAPHS) cnt[i] = 0;
    if (i == 0) *ovcnt = 0;
    if (i < NBK) bcur[i] = i * CAPB;
}

// ---------------- kB: bin edges into per-bucket regions (the one scatter pass)
__global__ __launch_bounds__(256) void kB(const int* __restrict__ src,
                                          const int* __restrict__ dst,
                                          int* __restrict__ bcur,
                                          unsigned* __restrict__ sorted,
                                          int* __restrict__ ovcnt,
                                          int2* __restrict__ ovlist) {
    __shared__ int hist[NBK];
    __shared__ int basep[NBK];
    int tid = threadIdx.x;
    int e0 = blockIdx.x * EPW;
    int ecnt = min(EPW, N_EDGES - e0);
    for (int i = tid; i < NBK; i += 256) hist[i] = 0;
    __syncthreads();
    for (int i = tid; i < ecnt; i += 256)
        atomicAdd(&hist[dst[e0 + i] >> BSH], 1);
    __syncthreads();
    for (int b = tid; b < NBK; b += 256) {
        int c = hist[b];
        basep[b] = c ? atomicAdd(&bcur[b], c) : 0;   // dense contended atomics
    }
    __syncthreads();
    for (int i = tid; i < ecnt; i += 256) {
        int s = src[e0 + i], d = dst[e0 + i];
        int b = d >> BSH;
        int pos = atomicAdd(&basep[b], 1);           // LDS bump
        if (pos < (b + 1) * CAPB)
            sorted[pos] = ((unsigned)s << BSH) | (unsigned)(d & (BNODES - 1));
        else {
            int oi = atomicAdd(ovcnt, 1);
            if (oi < OVCAP) ovlist[oi] = make_int2(s, d);
        }
    }
}

// ---------------- kdeg: per-bucket degree count -> deg, dis, u (no global zero)
__global__ __launch_bounds__(256) void kdeg(const int* __restrict__ bcur,
                                            const unsigned* __restrict__ sorted,
                                            const int* __restrict__ ovcnt,
                                            const int2* __restrict__ ovlist,
                                            const float* __restrict__ x,
                                            int* __restrict__ deg,
                                            float* __restrict__ dis,
                                            float* __restrict__ u) {
    __shared__ int dcnt[BNODES];
    int b = blockIdx.x, tid = threadIdx.x;
    if (tid < BNODES) dcnt[tid] = 0;
    __syncthreads();
    int s0 = b * CAPB;
    int cnt_b = min(bcur[b], (b + 1) * CAPB) - s0;
    for (int i = tid; i < cnt_b; i += 256)
        atomicAdd(&dcnt[sorted[s0 + i] & (BNODES - 1)], 1);
    int oc = min(*ovcnt, OVCAP);
    for (int i = tid; i < oc; i += 256) {
        int2 od = ovlist[i];
        if ((od.y >> BSH) == b) atomicAdd(&dcnt[od.y & (BNODES - 1)], 1);
    }
    __syncthreads();
    int n = b * BNODES + tid;
    if (tid < BNODES && n < N_NODES) {
        int dg = dcnt[tid];
        deg[n] = dg;
        float dn = rsqrtf((float)(dg + 1));
        dis[n] = dn;
        u[n] = dn * x[n];
    }
}

// ---------------- kq2: layer-1 per-bucket LDS reduce -> ad = (agg1, dis)
__global__ __launch_bounds__(256) void kq2(const int* __restrict__ bcur,
                                           const unsigned* __restrict__ sorted,
                                           const int* __restrict__ ovcnt,
                                           const int2* __restrict__ ovlist,
                                           const float* __restrict__ u,
                                           const float* __restrict__ x,
                                           const float* __restrict__ dis,
                                           const int* __restrict__ deg,
                                           float2* __restrict__ ad) {
    __shared__ float qL[BNODES];
    int b = blockIdx.x, tid = threadIdx.x;
    if (tid < BNODES) qL[tid] = 0.f;
    __syncthreads();
    int s0 = b * CAPB;
    int cnt_b = min(bcur[b], (b + 1) * CAPB) - s0;
    for (int i = tid; i < cnt_b; i += 256) {
        unsigned w = sorted[s0 + i];
        atomicAdd(&qL[w & (BNODES - 1)], u[w >> BSH]);
    }
    int oc = min(*ovcnt, OVCAP);
    for (int i = tid; i < oc; i += 256) {
        int2 od = ovlist[i];
        if ((od.y >> BSH) == b) atomicAdd(&qL[od.y & (BNODES - 1)], u[od.x]);
    }
    __syncthreads();
    int n = b * BNODES + tid;
    if (tid < BNODES && n < N_NODES) {
        float dn = dis[n];
        ad[n] = make_float2(dn * qL[tid] + x[n] / (float)(deg[n] + 1), dn);
    }
}

// ---------------- khist: layer-2 per-bucket LDS bucket-sums -> hist[k][n]
__global__ __launch_bounds__(256) void khist(const int* __restrict__ bcur,
                                             const unsigned* __restrict__ sorted,
                                             const int* __restrict__ ovcnt,
                                             const int2* __restrict__ ovlist,
                                             const float2* __restrict__ ad,
                                             const float* __restrict__ dt,
                                             const int* __restrict__ meta,
                                             float* __restrict__ histA,
                                             float* __restrict__ histW) {
    __shared__ float bA[8 * BNODES];
    __shared__ float bWs[8 * BNODES];
    __shared__ float dtS[8];
    int b = blockIdx.x, tid = threadIdx.x;
    int nd = meta[0], needW = meta[1];
    if (nd > 7) return;                       // knode handles general case
    if (tid < 8) dtS[tid] = (tid < nd) ? dt[tid] : 3.4e38f;
    for (int i = tid; i < (nd + 1) * BNODES; i += 256) { bA[i] = 0.f; bWs[i] = 0.f; }
    __syncthreads();
    int s0 = b * CAPB;
    int cnt_b = min(bcur[b], (b + 1) * CAPB) - s0;
    for (int i = tid; i < cnt_b; i += 256) {
        unsigned w = sorted[s0 + i];
        int ld = w & (BNODES - 1);
        float2 t = ad[w >> BSH];
        float a = t.x;
        int k = 0;
        #pragma unroll
        for (int q = 0; q < 7; ++q) k += (dtS[q] < a) ? 1 : 0;
        atomicAdd(&bA[k * BNODES + ld], t.y * a);
        if (needW) atomicAdd(&bWs[k * BNODES + ld], t.y);
    }
    int oc = min(*ovcnt, OVCAP);
    for (int i = tid; i < oc; i += 256) {
        int2 od = ovlist[i];
        if ((od.y >> BSH) == b) {
            float2 t = ad[od.x];
            float a = t.x;
            int k = 0;
            #pragma unroll
            for (int q = 0; q < 7; ++q) k += (dtS[q] < a) ? 1 : 0;
            int ld = od.y & (BNODES - 1);
            atomicAdd(&bA[k * BNODES + ld], t.y * a);
            if (needW) atomicAdd(&bWs[k * BNODES + ld], t.y);
        }
    }
    __syncthreads();
    int n = b * BNODES;
    for (int k = 0; k <= nd; ++k)
        for (int i = tid; i < BNODES; i += 256)
            if (n + i < N_NODES) {
                histA[(size_t)k * N_NODES + n + i] = bA[k * BNODES + i];
                if (needW) histW[(size_t)k * N_NODES + n + i] = bWs[k * BNODES + i];
            }
}

// ---- knode: hist walk -> agg2(areg) -> @W2+b2 -> relu -> pooled by graph runs
__global__ __launch_bounds__(64) void knode(
        const float* __restrict__ histA, const float* __restrict__ histW,
        const int* __restrict__ meta,
        const float* __restrict__ pw1, const float* __restrict__ pb1,
        const int* __restrict__ pdidx, const float* __restrict__ w2p,
        const float2* __restrict__ ad, const float* __restrict__ b2,
        const int* __restrict__ batch,
        const int* __restrict__ bcur, const unsigned* __restrict__ sorted,
        const int* __restrict__ ovcnt, const int2* __restrict__ ovlist,
        float* __restrict__ pool, int* __restrict__ cnt) {
    __shared__ float h2s[HDIM * 65];
    int lane = threadIdx.x;
    int n0 = blockIdx.x * 64;
    int nvalid = min(64, N_NODES - n0);
    int n = n0 + min(lane, nvalid - 1);
    int nd = meta[0], needW = meta[1];
    float2 adn = ad[n];
    float a_n = adn.x, d_n = adn.y;
    float areg[HDIM];

    if (nd <= 7) {
        float TA = 0.f, TW = 0.f;
        for (int k = 0; k <= nd; ++k) {
            TA += histA[(size_t)k * N_NODES + n];
            if (needW) TW += histW[(size_t)k * N_NODES + n];
        }
        float runA = 0.f, runW = 0.f;
        int cur = -1;
        #pragma unroll
        for (int jj = 0; jj < HDIM; ++jj) {
            int didx = pdidx[jj];                 // uniform, nondecreasing
            while (cur < didx) {
                ++cur;
                runA += histA[(size_t)cur * N_NODES + n];
                if (needW) runW += histW[(size_t)cur * N_NODES + n];
            }
            float w1 = pw1[jj], bb = pb1[jj];
            float nb;
            if (w1 > 0.f)      nb = w1 * (TA - runA) + bb * (TW - runW);
            else if (w1 < 0.f) nb = w1 * runA + bb * runW;
            else               nb = fmaxf(bb, 0.f) * TW;
            areg[jj] = d_n * nb + d_n * d_n * fmaxf(a_n * w1 + bb, 0.f);
        }
    } else {
        // correctness-only general path: scan my bucket's edge list (uniform reads)
        #pragma unroll
        for (int jj = 0; jj < HDIM; ++jj) areg[jj] = 0.f;
        int b = n >> BSH;                         // uniform across block (64 | 128)
        int myld = n & (BNODES - 1);
        int s0 = b * CAPB;
        int cnt_b = min(bcur[b], (b + 1) * CAPB) - s0;
        for (int i = 0; i < cnt_b; ++i) {
            unsigned w = sorted[s0 + i];
            if ((int)(w & (BNODES - 1)) == myld) {
                float2 t = ad[w >> BSH];
                #pragma unroll
                for (int jj = 0; jj < HDIM; ++jj)
                    areg[jj] += t.y * fmaxf(t.x * pw1[jj] + pb1[jj], 0.f);
            }
        }
        int oc = min(*ovcnt, OVCAP);
        for (int i = 0; i < oc; ++i) {
            int2 od = ovlist[i];
            if (od.y == n) {
                float2 t = ad[od.x];
                #pragma unroll
                for (int jj = 0; jj < HDIM; ++jj)
                    areg[jj] += t.y * fmaxf(t.x * pw1[jj] + pb1[jj], 0.f);
            }
        }
        #pragma unroll
        for (int jj = 0; jj < HDIM; ++jj)
            areg[jj] = d_n * areg[jj] + d_n * d_n * fmaxf(a_n * pw1[jj] + pb1[jj], 0.f);
    }

    // h2 = relu(agg2 @ W2 + b2): 4 chunks of 16, register accumulators, uniform W rows
    #pragma unroll
    for (int c = 0; c < 4; ++c) {
        float acc[16];
        #pragma unroll
        for (int t = 0; t < 16; ++t) acc[t] = b2[c * 16 + t];
        #pragma unroll
        for (int jj = 0; jj < HDIM; ++jj) {
            float av = areg[jj];
            const float* wrow = w2p + jj * HDIM + c * 16;
            #pragma unroll
            for (int t = 0; t < 16; ++t) acc[t] += av * wrow[t];
        }
        #pragma unroll
        for (int t = 0; t < 16; ++t)
            h2s[lane * 65 + c * 16 + t] = fmaxf(acc[t], 0.f);
    }

    // pool phase: lane = channel; nodes sorted by graph -> batched run flush
    float accP = 0.f; int gcur = -1, runC = 0;
    for (int i = 0; i < nvalid; ++i) {
        int g = batch[n0 + i];
        float v = h2s[i * 65 + lane];
        if (g != gcur) {
            if (gcur >= 0) {
                atomicAdd(&pool[(size_t)gcur * HDIM + lane], accP);
                if (lane == 0) atomicAdd(&cnt[gcur], runC);
            }
            gcur = g; accP = 0.f; runC = 0;
        }
        accP += v; ++runC;
    }
    if (gcur >= 0) {
        atomicAdd(&pool[(size_t)gcur * HDIM + lane], accP);
        if (lane == 0) atomicAdd(&cnt[gcur], runC);
    }
}

// ---------------- final MLP per graph
__global__ void k7_mlp(const float* __restrict__ pool, const int* __restrict__ cnt,
                       const float* __restrict__ fW1, const float* __restrict__ fb1,
                       const float* __restrict__ fW2, const float* __restrict__ fb2,
                       float* __restrict__ out) {
    __shared__ float p[HDIM];
    __shared__ float tt[32];
    int g = blockIdx.x;
    int tid = threadIdx.x;
    float c = fmaxf((float)cnt[g], 1.f);
    p[tid] = pool[g * HDIM + tid] / c;
    __syncthreads();
    if (tid < 32) {
        float acc = fb1[tid];
        #pragma unroll
        for (int j = 0; j < HDIM; ++j) acc += p[j] * fW1[j * 32 + tid];
        tt[tid] = fmaxf(acc, 0.f);
    }
    __syncthreads();
    if (tid < 7) {
        float acc = fb2[tid];
        #pragma unroll
        for (int i = 0; i < 32; ++i) acc += tt[i] * fW2[i * 7 + tid];
        out[g * 7 + tid] = acc;
    }
}

// =================== fallback path (round-1 kernels, if ws too small) ===================
__global__ void kf1_deg(const int* __restrict__ dst, int* __restrict__ deg) {
    int e = blockIdx.x * blockDim.x + threadIdx.x;
    if (e < N_EDGES) atomicAdd(&deg[dst[e]], 1);
}
__global__ void kf2_dis(const int* __restrict__ deg, const float* __restrict__ x,
                        float* __restrict__ dis, float* __restrict__ agg1) {
    int n = blockIdx.x * blockDim.x + threadIdx.x;
    if (n < N_NODES) {
        float d = (float)(deg[n] + 1);
        dis[n] = rsqrtf(d);
        agg1[n] = x[n] / d;
    }
}
__global__ void kf3_agg1(const int* __restrict__ src, const int* __restrict__ dst,
                         const float* __restrict__ dis, const float* __restrict__ x,
                         float* __restrict__ agg1) {
    int e = blockIdx.x * blockDim.x + threadIdx.x;
    if (e < N_EDGES) {
        int s = src[e], d = dst[e];
        atomicAdd(&agg1[d], dis[s] * dis[d] * x[s]);
    }
}
__global__ void kf4_agg2init(const float* __restrict__ agg1, const float* __restrict__ dis,
                             const float* __restrict__ W1, const float* __restrict__ b1,
                             float* __restrict__ agg2) {
    int i = blockIdx.x * blockDim.x + threadIdx.x;
    if (i < N_NODES * HDIM) {
        int n = i >> 6, j = i & 63;
        float h = fmaxf(agg1[n] * W1[j] + b1[j], 0.f);
        float r = dis[n];
        agg2[i] = r * r * h;
    }
}
__global__ void kf5_edge(const int* __restrict__ src, const int* __restrict__ dst,
                         const float* __restrict__ dis, const float* __restrict__ agg1,
                         const float* __restrict__ W1, const float* __restrict__ b1,
                         float* __restrict__ agg2) {
    int t = blockIdx.x * blockDim.x + threadIdx.x;
    int e = t >> 6, j = t & 63;
    if (e < N_EDGES) {
        int s = src[e], d = dst[e];
        float w = dis[s] * dis[d];
        float h = fmaxf(agg1[s] * W1[j] + b1[j], 0.f);
        atomicAdd(&agg2[d * HDIM + j], w * h);
    }
}
__global__ void kf6_pool(const float* __restrict__ agg2, const float* __restrict__ W2,
                         const float* __restrict__ b2, const int* __restrict__ batch,
                         float* __restrict__ pool, int* __restrict__ cnt) {
    __shared__ float w2s[HDIM * HDIM];
    int tid = threadIdx.x;
    for (int i = tid; i < HDIM * HDIM; i += blockDim.x) w2s[i] = W2[i];
    __syncthreads();
    int lane = tid & 63, wid = tid >> 6;
    int nwaves = gridDim.x * 4;
    for (int n = blockIdx.x * 4 + wid; n < N_NODES; n += nwaves) {
        float av  = agg2[n * HDIM + lane];
        float acc = b2[lane];
        #pragma unroll
        for (int k = 0; k < HDIM; ++k)
            acc += __shfl(av, k, 64) * w2s[k * HDIM + lane];
        acc = fmaxf(acc, 0.f);
        int g = batch[n];
        atomicAdd(&pool[g * HDIM + lane], acc);
        if (lane == 0) atomicAdd(&cnt[g], 1);
    }
}

// ----------------------------------------------------------------------------
extern "C" void kernel_launch(void* const* d_in, const int* in_sizes, int n_in,
                              void* d_out, int out_size, void* d_ws, size_t ws_size,
                              hipStream_t stream) {
    const float* x    = (const float*)d_in[0];
    const int*   ei   = (const int*)  d_in[1];
    const int*   batch= (const int*)  d_in[2];
    const float* W1   = (const float*)d_in[3];
    const float* b1   = (const float*)d_in[4];
    const float* W2   = (const float*)d_in[5];
    const float* b2   = (const float*)d_in[6];
    const float* fW1  = (const float*)d_in[7];
    const float* fb1  = (const float*)d_in[8];
    const float* fW2  = (const float*)d_in[9];
    const float* fb2  = (const float*)d_in[10];
    const int* src = ei;
    const int* dst = ei + N_EDGES;
    float* out = (float*)d_out;

    size_t off = 0;
    auto take = [&](size_t bytes) { size_t o = off; off = (off + bytes + 255) & ~(size_t)255; return o; };
    char* base = (char*)d_ws;
    int*     deg   = (int*)     (base + take((size_t)N_NODES * 4));
    float*   pool  = (float*)   (base + take((size_t)G_GRAPHS * HDIM * 4));
    int*     cnt   = (int*)     (base + take((size_t)G_GRAPHS * 4));
    int*     ovcnt = (int*)     (base + take(4));
    float*   dis   = (float*)   (base + take((size_t)N_NODES * 4));
    float*   u     = (float*)   (base + take((size_t)N_NODES * 4));
    float2*  ad    = (float2*)  (base + take((size_t)N_NODES * 8));
    float*   dt    = (float*)   (base + take(HDIM * 4));
    int*     rankd = (int*)     (base + take(HDIM * 4));
    int*     kperm = (int*)     (base + take(HDIM * 4));
    int*     meta  = (int*)     (base + take(64));
    float*   pw1   = (float*)   (base + take(HDIM * 4));
    float*   pb1   = (float*)   (base + take(HDIM * 4));
    int*     pdidx = (int*)     (base + take(HDIM * 4));
    float*   w2p   = (float*)   (base + take(HDIM * HDIM * 4));
    int*     bcur  = (int*)     (base + take(NBK * 4));
    int2*    ovlist= (int2*)    (base + take((size_t)OVCAP * 8));
    size_t sorted_off = off;
    unsigned* sorted = (unsigned*)(base + take((size_t)NBK * CAPB * 4));
    float*   histA = (float*)   (base + take((size_t)8 * N_NODES * 4));
    float*   histW = (float*)   (base + take((size_t)8 * N_NODES * 4));
    size_t need_fast = off;

    if (ws_size >= need_fast) {
        kzero <<<(G_GRAPHS * HDIM + 255) / 256, 256, 0, stream>>>(pool, cnt, ovcnt, bcur);
        kprep <<<1, HDIM, 0, stream>>>(W1, b1, dt, rankd, kperm, meta);
        kprep2<<<16, 256, 0, stream>>>(W1, b1, kperm, rankd, W2, w2p, pw1, pb1, pdidx);
        kB    <<<(N_EDGES + EPW - 1) / EPW, 256, 0, stream>>>(src, dst, bcur, sorted, ovcnt, ovlist);
        kdeg  <<<NBK, 256, 0, stream>>>(bcur, sorted, ovcnt, ovlist, x, deg, dis, u);
        kq2   <<<NBK, 256, 0, stream>>>(bcur, sorted, ovcnt, ovlist, u, x, dis, deg, ad);
        khist <<<NBK, 256, 0, stream>>>(bcur, sorted, ovcnt, ovlist, ad, dt, meta, histA, histW);
        knode <<<(N_NODES + 63) / 64, 64, 0, stream>>>(histA, histW, meta, pw1, pb1, pdidx,
                                                       w2p, ad, b2, batch,
                                                       bcur, sorted, ovcnt, ovlist, pool, cnt);
        k7_mlp<<<G_GRAPHS, 64, 0, stream>>>(pool, cnt, fW1, fb1, fW2, fb2, out);
    } else {
        // fallback: R1 pipeline; agg1 in u, agg2 in the sorted/hist region
        float* agg1 = u;
        float* agg2 = (float*)(base + sorted_off);
        size_t zero_bytes = (size_t)N_NODES * 4;   // deg
        hipMemsetAsync(deg, 0, zero_bytes, stream);
        hipMemsetAsync(pool, 0, (size_t)G_GRAPHS * HDIM * 4 + 1024, stream);
        kf1_deg<<<(N_EDGES + 255) / 256, 256, 0, stream>>>(dst, deg);
        kf2_dis<<<(N_NODES + 255) / 256, 256, 0, stream>>>(deg, x, dis, agg1);
        kf3_agg1<<<(N_EDGES + 255) / 256, 256, 0, stream>>>(src, dst, dis, x, agg1);
        kf4_agg2init<<<(N_NODES * HDIM + 255) / 256, 256, 0, stream>>>(agg1, dis, W1, b1, agg2);
        int k5_blocks = (int)(((long long)N_EDGES * HDIM + 255) / 256);
        kf5_edge<<<k5_blocks, 256, 0, stream>>>(src, dst, dis, agg1, W1, b1, agg2);
        kf6_pool<<<2048, 256, 0, stream>>>(agg2, W2, b2, batch, pool, cnt);
        k7_mlp<<<G_GRAPHS, 64, 0, stream>>>(pool, cnt, fW1, fb1, fW2, fb2, out);
    }
}

// Round 7
// 162.084 us; speedup vs baseline: 7.0802x; 1.0647x over previous
//
#include <hip/hip_runtime.h>

#define N_NODES 100000
#define N_EDGES 3200000
#define G_GRAPHS 512
#define HDIM 64
#define BSH 7                  // 128 nodes per bucket
#define BNODES 128
#define NBK ((N_NODES + BNODES - 1) / BNODES)   // 782
#define CAPB 6144              // slots/bucket: mean 4096, +32 sigma
#define OVCAP 65536
#define EPW 8192               // edges per workgroup in kB
#define MAXROWS 29             // 1 + 4*7 table rows

// ---------------- kprep: distinct relu thresholds, ranks, perm, flags
__global__ void kprep(const float* __restrict__ W1, const float* __restrict__ b1,
                      float* __restrict__ dt, int* __restrict__ rank_d,
                      int* __restrict__ kperm, int* __restrict__ meta) {
    __shared__ float ts[HDIM], srt[HDIM];
    __shared__ int isnew[HDIM], bW[HDIM];
    int j = threadIdx.x;
    float w1 = W1[j], bb = b1[j];
    float tj = (w1 != 0.f) ? (-bb / w1) : -1e30f;
    ts[j] = tj;
    bW[j] = (bb != 0.f) ? 1 : 0;
    __syncthreads();
    int r = 0;
    for (int i = 0; i < HDIM; ++i) {
        float ti = ts[i];
        if (ti < tj || (ti == tj && i < j)) r++;
    }
    srt[r] = tj;
    kperm[r] = j;
    __syncthreads();
    isnew[r] = (r == 0) || (srt[r] != srt[r - 1]);
    __syncthreads();
    int didx = 0;
    for (int q = 0; q <= r; ++q) didx += isnew[q];
    didx -= 1;
    if (isnew[r]) dt[didx] = srt[r];
    rank_d[j] = didx;
    if (j == 0) {
        int nd = 0, nw = 0;
        for (int q = 0; q < HDIM; ++q) { nd += isnew[q]; nw |= bW[q]; }
        meta[0] = nd;
        meta[1] = nw;
    }
}

// ---------------- kprep2: permuted params (general nd>7 path only)
__global__ void kprep2(const float* __restrict__ W1, const float* __restrict__ b1,
                       const int* __restrict__ kperm, const int* __restrict__ rank_d,
                       const float* __restrict__ W2,
                       float* __restrict__ w2p, float* __restrict__ pw1,
                       float* __restrict__ pb1, int* __restrict__ pdidx) {
    int i = blockIdx.x * blockDim.x + threadIdx.x;
    if (i < HDIM * HDIM) {
        int r = i >> 6, j2 = i & 63;
        int j = kperm[r];
        w2p[i] = W2[j * HDIM + j2];
        if (j2 == 0) { pw1[r] = W1[j]; pb1[r] = b1[j]; pdidx[r] = rank_d[j]; }
    }
}

// ---------------- kprep3: fold W1/b1/relu-groups into W2 row-combination tables
// rows (x64 floats): 0 = vC; per delta d8: 1+4*d8 = vWp, +1 vWm, +2 vBp, +3 vBm
__global__ void kprep3(const float* __restrict__ W1, const float* __restrict__ b1,
                       const float* __restrict__ W2, const int* __restrict__ rank_d,
                       const int* __restrict__ meta, float* __restrict__ tabs) {
    __shared__ float tabL[MAXROWS * HDIM];
    int t = threadIdx.x;                      // 64 threads = 1 wave
    int nd = meta[0];
    if (nd > 7) return;
    int nrows = 1 + 4 * nd;
    for (int r = 0; r < nrows; ++r) tabL[r * HDIM + t] = 0.f;
    for (int j = 0; j < HDIM; ++j) {
        float w1 = W1[j], bb = b1[j];
        float wr = W2[j * HDIM + t];
        if (w1 == 0.f) {
            tabL[t] += fmaxf(bb, 0.f) * wr;                 // vC
        } else {
            int base = (1 + 4 * rank_d[j]) * HDIM + t;
            if (w1 > 0.f) { tabL[base] += w1 * wr; tabL[base + 2 * HDIM] += bb * wr; }
            else          { tabL[base + HDIM] += w1 * wr; tabL[base + 3 * HDIM] += bb * wr; }
        }
    }
    for (int r = 0; r < nrows; ++r) tabs[r * HDIM + t] = tabL[r * HDIM + t];
}

// ---------------- kzero: small accumulators + bucket bump pointers
__global__ void kzero(float* __restrict__ pool, int* __restrict__ cnt,
                      int* __restrict__ ovcnt, int* __restrict__ bcur) {
    int i = blockIdx.x * blockDim.x + threadIdx.x;
    if (i < G_GRAPHS * HDIM) pool[i] = 0.f;
    if (i < G_GRAPHS) cnt[i] = 0;
    if (i == 0) *ovcnt = 0;
    if (i < NBK) bcur[i] = i * CAPB;
}

// ---------------- kB: bin edges into per-bucket regions (the one scatter pass)
__global__ __launch_bounds__(256) void kB(const int* __restrict__ src,
                                          const int* __restrict__ dst,
                                          int* __restrict__ bcur,
                                          unsigned* __restrict__ sorted,
                                          int* __restrict__ ovcnt,
                                          int2* __restrict__ ovlist) {
    __shared__ int hist[NBK];
    __shared__ int basep[NBK];
    int tid = threadIdx.x;
    int e0 = blockIdx.x * EPW;
    int ecnt = min(EPW, N_EDGES - e0);
    for (int i = tid; i < NBK; i += 256) hist[i] = 0;
    __syncthreads();
    for (int i = tid; i < ecnt; i += 256)
        atomicAdd(&hist[dst[e0 + i] >> BSH], 1);
    __syncthreads();
    for (int b = tid; b < NBK; b += 256) {
        int c = hist[b];
        basep[b] = c ? atomicAdd(&bcur[b], c) : 0;
    }
    __syncthreads();
    for (int i = tid; i < ecnt; i += 256) {
        int s = src[e0 + i], d = dst[e0 + i];
        int b = d >> BSH;
        int pos = atomicAdd(&basep[b], 1);
        if (pos < (b + 1) * CAPB)
            sorted[pos] = ((unsigned)s << BSH) | (unsigned)(d & (BNODES - 1));
        else {
            int oi = atomicAdd(ovcnt, 1);
            if (oi < OVCAP) ovlist[oi] = make_int2(s, d);
        }
    }
}

// ---------------- kdeg: per-bucket degree count -> deg, dis, u
__global__ __launch_bounds__(256) void kdeg(const int* __restrict__ bcur,
                                            const unsigned* __restrict__ sorted,
                                            const int* __restrict__ ovcnt,
                                            const int2* __restrict__ ovlist,
                                            const float* __restrict__ x,
                                            int* __restrict__ deg,
                                            float* __restrict__ dis,
                                            float* __restrict__ u) {
    __shared__ int dcnt[BNODES];
    int b = blockIdx.x, tid = threadIdx.x;
    if (tid < BNODES) dcnt[tid] = 0;
    __syncthreads();
    int s0 = b * CAPB;
    int cnt_b = min(bcur[b], (b + 1) * CAPB) - s0;
    for (int i = tid; i < cnt_b; i += 256)
        atomicAdd(&dcnt[sorted[s0 + i] & (BNODES - 1)], 1);
    int oc = min(*ovcnt, OVCAP);
    for (int i = tid; i < oc; i += 256) {
        int2 od = ovlist[i];
        if ((od.y >> BSH) == b) atomicAdd(&dcnt[od.y & (BNODES - 1)], 1);
    }
    __syncthreads();
    int n = b * BNODES + tid;
    if (tid < BNODES && n < N_NODES) {
        int dg = dcnt[tid];
        deg[n] = dg;
        float dn = rsqrtf((float)(dg + 1));
        dis[n] = dn;
        u[n] = dn * x[n];
    }
}

// ---------------- kq2: layer-1 per-bucket LDS reduce -> ad = (agg1, dis)
__global__ __launch_bounds__(256) void kq2(const int* __restrict__ bcur,
                                           const unsigned* __restrict__ sorted,
                                           const int* __restrict__ ovcnt,
                                           const int2* __restrict__ ovlist,
                                           const float* __restrict__ u,
                                           const float* __restrict__ x,
                                           const float* __restrict__ dis,
                                           const int* __restrict__ deg,
                                           float2* __restrict__ ad) {
    __shared__ float qL[BNODES];
    int b = blockIdx.x, tid = threadIdx.x;
    if (tid < BNODES) qL[tid] = 0.f;
    __syncthreads();
    int s0 = b * CAPB;
    int cnt_b = min(bcur[b], (b + 1) * CAPB) - s0;
    for (int i = tid; i < cnt_b; i += 256) {
        unsigned w = sorted[s0 + i];
        atomicAdd(&qL[w & (BNODES - 1)], u[w >> BSH]);
    }
    int oc = min(*ovcnt, OVCAP);
    for (int i = tid; i < oc; i += 256) {
        int2 od = ovlist[i];
        if ((od.y >> BSH) == b) atomicAdd(&qL[od.y & (BNODES - 1)], u[od.x]);
    }
    __syncthreads();
    int n = b * BNODES + tid;
    if (tid < BNODES && n < N_NODES) {
        float dn = dis[n];
        ad[n] = make_float2(dn * qL[tid] + x[n] / (float)(deg[n] + 1), dn);
    }
}

// ---------------- khist: layer-2 per-bucket LDS bucket-sums -> hist[k][n]
__global__ __launch_bounds__(256) void khist(const int* __restrict__ bcur,
                                             const unsigned* __restrict__ sorted,
                                             const int* __restrict__ ovcnt,
                                             const int2* __restrict__ ovlist,
                                             const float2* __restrict__ ad,
                                             const float* __restrict__ dt,
                                             const int* __restrict__ meta,
                                             float* __restrict__ histA,
                                             float* __restrict__ histW) {
    __shared__ float bA[8 * BNODES];
    __shared__ float bWs[8 * BNODES];
    __shared__ float dtS[8];
    int b = blockIdx.x, tid = threadIdx.x;
    int nd = meta[0], needW = meta[1];
    if (nd > 7) return;                       // knode handles general case
    if (tid < 8) dtS[tid] = (tid < nd) ? dt[tid] : 3.4e38f;
    for (int i = tid; i < (nd + 1) * BNODES; i += 256) { bA[i] = 0.f; bWs[i] = 0.f; }
    __syncthreads();
    int s0 = b * CAPB;
    int cnt_b = min(bcur[b], (b + 1) * CAPB) - s0;
    for (int i = tid; i < cnt_b; i += 256) {
        unsigned w = sorted[s0 + i];
        int ld = w & (BNODES - 1);
        float2 t = ad[w >> BSH];
        float a = t.x;
        int k = 0;
        #pragma unroll
        for (int q = 0; q < 7; ++q) k += (dtS[q] < a) ? 1 : 0;
        atomicAdd(&bA[k * BNODES + ld], t.y * a);
        if (needW) atomicAdd(&bWs[k * BNODES + ld], t.y);
    }
    int oc = min(*ovcnt, OVCAP);
    for (int i = tid; i < oc; i += 256) {
        int2 od = ovlist[i];
        if ((od.y >> BSH) == b) {
            float2 t = ad[od.x];
            float a = t.x;
            int k = 0;
            #pragma unroll
            for (int q = 0; q < 7; ++q) k += (dtS[q] < a) ? 1 : 0;
            int ld = od.y & (BNODES - 1);
            atomicAdd(&bA[k * BNODES + ld], t.y * a);
            if (needW) atomicAdd(&bWs[k * BNODES + ld], t.y);
        }
    }
    __syncthreads();
    int n = b * BNODES;
    for (int k = 0; k <= nd; ++k)
        for (int i = tid; i < BNODES; i += 256)
            if (n + i < N_NODES) {
                histA[(size_t)k * N_NODES + n + i] = bA[k * BNODES + i];
                if (needW) histW[(size_t)k * N_NODES + n + i] = bWs[k * BNODES + i];
            }
}

// ---- knode v3: 256 thr = 64 nodes x 4 channel-chunks; table-folded z; LDS pool
__global__ __launch_bounds__(256) void knode(
        const float* __restrict__ histA, const float* __restrict__ histW,
        const int* __restrict__ meta, const float* __restrict__ dt,
        const float* __restrict__ tabs,
        const float* __restrict__ pw1, const float* __restrict__ pb1,
        const float* __restrict__ w2p,
        const float2* __restrict__ ad, const float* __restrict__ b2,
        const int* __restrict__ batch,
        const int* __restrict__ bcur, const unsigned* __restrict__ sorted,
        const int* __restrict__ ovcnt, const int2* __restrict__ ovlist,
        float* __restrict__ pool, int* __restrict__ cnt) {
    __shared__ float h2s[HDIM * 65];
    __shared__ float tabL[MAXROWS * HDIM];
    __shared__ float dtS[8];
    int tid = threadIdx.x;
    int nl = tid & 63, cg = tid >> 6;
    int n0 = blockIdx.x * 64;
    int nvalid = min(64, N_NODES - n0);
    int n = n0 + min(nl, nvalid - 1);
    int nd = meta[0], needW = meta[1];
    float2 adn = ad[n];
    float a = adn.x, d = adn.y;
    int c16 = cg * 16;

    if (nd <= 7) {
        int nrows = 1 + 4 * nd;
        for (int i = tid; i < nrows * HDIM; i += 256) tabL[i] = tabs[i];
        if (tid < nd) dtS[tid] = dt[tid];
        __syncthreads();
        float TA = 0.f, TW = 0.f;
        for (int b = 0; b <= nd; ++b) {
            TA += histA[(size_t)b * N_NODES + n];
            if (needW) TW += histW[(size_t)b * N_NODES + n];
        }
        int k = 0;
        for (int q = 0; q < nd; ++q) k += (dtS[q] < a) ? 1 : 0;
        float z[16];
        #pragma unroll
        for (int t = 0; t < 16; ++t) z[t] = b2[c16 + t];
        float d2 = d * d;
        float cC = d * TW + d2;
        #pragma unroll
        for (int t = 0; t < 16; ++t) z[t] += cC * tabL[c16 + t];
        float run = 0.f, runW = 0.f;
        for (int q = 0; q < nd; ++q) {
            run += histA[(size_t)q * N_NODES + n];
            if (needW) runW += histW[(size_t)q * N_NODES + n];
            bool act = (q < k);                       // self-loop relu active side
            float cWp = d * (TA - run) + (act ? d2 * a : 0.f);
            float cWm = d * run + (act ? 0.f : d2 * a);
            float cBp = d * (TW - runW) + (act ? d2 : 0.f);
            float cBm = d * runW + (act ? 0.f : d2);
            int base = (1 + 4 * q) * HDIM + c16;
            #pragma unroll
            for (int t = 0; t < 16; ++t)
                z[t] += cWp * tabL[base + t] + cWm * tabL[base + HDIM + t]
                      + cBp * tabL[base + 2 * HDIM + t] + cBm * tabL[base + 3 * HDIM + t];
        }
        #pragma unroll
        for (int t = 0; t < 16; ++t) h2s[nl * 65 + c16 + t] = fmaxf(z[t], 0.f);
    } else {
        // correctness-only general path: bucket-list scan, direct 64-ch evaluation
        float areg[HDIM];
        #pragma unroll
        for (int jj = 0; jj < HDIM; ++jj) areg[jj] = 0.f;
        int b = n >> BSH;
        int myld = n & (BNODES - 1);
        int s0 = b * CAPB;
        int cnt_b = min(bcur[b], (b + 1) * CAPB) - s0;
        for (int i = 0; i < cnt_b; ++i) {
            unsigned w = sorted[s0 + i];
            if ((int)(w & (BNODES - 1)) == myld) {
                float2 t = ad[w >> BSH];
                #pragma unroll
                for (int jj = 0; jj < HDIM; ++jj)
                    areg[jj] += t.y * fmaxf(t.x * pw1[jj] + pb1[jj], 0.f);
            }
        }
        int oc = min(*ovcnt, OVCAP);
        for (int i = 0; i < oc; ++i) {
            int2 od = ovlist[i];
            if (od.y == n) {
                float2 t = ad[od.x];
                #pragma unroll
                for (int jj = 0; jj < HDIM; ++jj)
                    areg[jj] += t.y * fmaxf(t.x * pw1[jj] + pb1[jj], 0.f);
            }
        }
        #pragma unroll
        for (int jj = 0; jj < HDIM; ++jj)
            areg[jj] = d * areg[jj] + d * d * fmaxf(a * pw1[jj] + pb1[jj], 0.f);
        float z[16];
        #pragma unroll
        for (int t = 0; t < 16; ++t) z[t] = b2[c16 + t];
        for (int jj = 0; jj < HDIM; ++jj) {
            float av = areg[jj];
            #pragma unroll
            for (int t = 0; t < 16; ++t) z[t] += av * w2p[jj * HDIM + c16 + t];
        }
        #pragma unroll
        for (int t = 0; t < 16; ++t) h2s[nl * 65 + c16 + t] = fmaxf(z[t], 0.f);
    }

    __syncthreads();
    // pool: wave cg handles nodes [16cg, 16cg+16); lane = channel
    int i0 = cg * 16, i1 = min(i0 + 16, nvalid);
    float accP = 0.f; int gcur = -1, runC = 0;
    for (int i = i0; i < i1; ++i) {
        int g = batch[n0 + i];
        float v = h2s[i * 65 + nl];
        if (g != gcur) {
            if (gcur >= 0) {
                atomicAdd(&pool[(size_t)gcur * HDIM + nl], accP);
                if (nl == 0) atomicAdd(&cnt[gcur], runC);
            }
            gcur = g; accP = 0.f; runC = 0;
        }
        accP += v; ++runC;
    }
    if (gcur >= 0) {
        atomicAdd(&pool[(size_t)gcur * HDIM + nl], accP);
        if (nl == 0) atomicAdd(&cnt[gcur], runC);
    }
}

// ---------------- final MLP per graph
__global__ void k7_mlp(const float* __restrict__ pool, const int* __restrict__ cnt,
                       const float* __restrict__ fW1, const float* __restrict__ fb1,
                       const float* __restrict__ fW2, const float* __restrict__ fb2,
                       float* __restrict__ out) {
    __shared__ float p[HDIM];
    __shared__ float tt[32];
    int g = blockIdx.x;
    int tid = threadIdx.x;
    float c = fmaxf((float)cnt[g], 1.f);
    p[tid] = pool[g * HDIM + tid] / c;
    __syncthreads();
    if (tid < 32) {
        float acc = fb1[tid];
        #pragma unroll
        for (int j = 0; j < HDIM; ++j) acc += p[j] * fW1[j * 32 + tid];
        tt[tid] = fmaxf(acc, 0.f);
    }
    __syncthreads();
    if (tid < 7) {
        float acc = fb2[tid];
        #pragma unroll
        for (int i = 0; i < 32; ++i) acc += tt[i] * fW2[i * 7 + tid];
        out[g * 7 + tid] = acc;
    }
}

// =================== fallback path (round-1 kernels, if ws too small) ===================
__global__ void kf1_deg(const int* __restrict__ dst, int* __restrict__ deg) {
    int e = blockIdx.x * blockDim.x + threadIdx.x;
    if (e < N_EDGES) atomicAdd(&deg[dst[e]], 1);
}
__global__ void kf2_dis(const int* __restrict__ deg, const float* __restrict__ x,
                        float* __restrict__ dis, float* __restrict__ agg1) {
    int n = blockIdx.x * blockDim.x + threadIdx.x;
    if (n < N_NODES) {
        float d = (float)(deg[n] + 1);
        dis[n] = rsqrtf(d);
        agg1[n] = x[n] / d;
    }
}
__global__ void kf3_agg1(const int* __restrict__ src, const int* __restrict__ dst,
                         const float* __restrict__ dis, const float* __restrict__ x,
                         float* __restrict__ agg1) {
    int e = blockIdx.x * blockDim.x + threadIdx.x;
    if (e < N_EDGES) {
        int s = src[e], d = dst[e];
        atomicAdd(&agg1[d], dis[s] * dis[d] * x[s]);
    }
}
__global__ void kf4_agg2init(const float* __restrict__ agg1, const float* __restrict__ dis,
                             const float* __restrict__ W1, const float* __restrict__ b1,
                             float* __restrict__ agg2) {
    int i = blockIdx.x * blockDim.x + threadIdx.x;
    if (i < N_NODES * HDIM) {
        int n = i >> 6, j = i & 63;
        float h = fmaxf(agg1[n] * W1[j] + b1[j], 0.f);
        float r = dis[n];
        agg2[i] = r * r * h;
    }
}
__global__ void kf5_edge(const int* __restrict__ src, const int* __restrict__ dst,
                         const float* __restrict__ dis, const float* __restrict__ agg1,
                         const float* __restrict__ W1, const float* __restrict__ b1,
                         float* __restrict__ agg2) {
    int t = blockIdx.x * blockDim.x + threadIdx.x;
    int e = t >> 6, j = t & 63;
    if (e < N_EDGES) {
        int s = src[e], d = dst[e];
        float w = dis[s] * dis[d];
        float h = fmaxf(agg1[s] * W1[j] + b1[j], 0.f);
        atomicAdd(&agg2[d * HDIM + j], w * h);
    }
}
__global__ void kf6_pool(const float* __restrict__ agg2, const float* __restrict__ W2,
                         const float* __restrict__ b2, const int* __restrict__ batch,
                         float* __restrict__ pool, int* __restrict__ cnt) {
    __shared__ float w2s[HDIM * HDIM];
    int tid = threadIdx.x;
    for (int i = tid; i < HDIM * HDIM; i += blockDim.x) w2s[i] = W2[i];
    __syncthreads();
    int lane = tid & 63, wid = tid >> 6;
    int nwaves = gridDim.x * 4;
    for (int n = blockIdx.x * 4 + wid; n < N_NODES; n += nwaves) {
        float av  = agg2[n * HDIM + lane];
        float acc = b2[lane];
        #pragma unroll
        for (int k = 0; k < HDIM; ++k)
            acc += __shfl(av, k, 64) * w2s[k * HDIM + lane];
        acc = fmaxf(acc, 0.f);
        int g = batch[n];
        atomicAdd(&pool[g * HDIM + lane], acc);
        if (lane == 0) atomicAdd(&cnt[g], 1);
    }
}

// ----------------------------------------------------------------------------
extern "C" void kernel_launch(void* const* d_in, const int* in_sizes, int n_in,
                              void* d_out, int out_size, void* d_ws, size_t ws_size,
                              hipStream_t stream) {
    const float* x    = (const float*)d_in[0];
    const int*   ei   = (const int*)  d_in[1];
    const int*   batch= (const int*)  d_in[2];
    const float* W1   = (const float*)d_in[3];
    const float* b1   = (const float*)d_in[4];
    const float* W2   = (const float*)d_in[5];
    const float* b2   = (const float*)d_in[6];
    const float* fW1  = (const float*)d_in[7];
    const float* fb1  = (const float*)d_in[8];
    const float* fW2  = (const float*)d_in[9];
    const float* fb2  = (const float*)d_in[10];
    const int* src = ei;
    const int* dst = ei + N_EDGES;
    float* out = (float*)d_out;

    size_t off = 0;
    auto take = [&](size_t bytes) { size_t o = off; off = (off + bytes + 255) & ~(size_t)255; return o; };
    char* base = (char*)d_ws;
    int*     deg   = (int*)     (base + take((size_t)N_NODES * 4));
    float*   pool  = (float*)   (base + take((size_t)G_GRAPHS * HDIM * 4));
    int*     cnt   = (int*)     (base + take((size_t)G_GRAPHS * 4));
    int*     ovcnt = (int*)     (base + take(4));
    float*   dis   = (float*)   (base + take((size_t)N_NODES * 4));
    float*   u     = (float*)   (base + take((size_t)N_NODES * 4));
    float2*  ad    = (float2*)  (base + take((size_t)N_NODES * 8));
    float*   dt    = (float*)   (base + take(HDIM * 4));
    int*     rankd = (int*)     (base + take(HDIM * 4));
    int*     kperm = (int*)     (base + take(HDIM * 4));
    int*     meta  = (int*)     (base + take(64));
    float*   pw1   = (float*)   (base + take(HDIM * 4));
    float*   pb1   = (float*)   (base + take(HDIM * 4));
    int*     pdidx = (int*)     (base + take(HDIM * 4));
    float*   w2p   = (float*)   (base + take(HDIM * HDIM * 4));
    float*   tabs  = (float*)   (base + take((size_t)32 * HDIM * 4));
    int*     bcur  = (int*)     (base + take(NBK * 4));
    int2*    ovlist= (int2*)    (base + take((size_t)OVCAP * 8));
    size_t sorted_off = off;
    unsigned* sorted = (unsigned*)(base + take((size_t)NBK * CAPB * 4));
    float*   histA = (float*)   (base + take((size_t)8 * N_NODES * 4));
    float*   histW = (float*)   (base + take((size_t)8 * N_NODES * 4));
    size_t need_fast = off;

    if (ws_size >= need_fast) {
        kzero <<<(G_GRAPHS * HDIM + 255) / 256, 256, 0, stream>>>(pool, cnt, ovcnt, bcur);
        kprep <<<1, HDIM, 0, stream>>>(W1, b1, dt, rankd, kperm, meta);
        kprep2<<<16, 256, 0, stream>>>(W1, b1, kperm, rankd, W2, w2p, pw1, pb1, pdidx);
        kprep3<<<1, HDIM, 0, stream>>>(W1, b1, W2, rankd, meta, tabs);
        kB    <<<(N_EDGES + EPW - 1) / EPW, 256, 0, stream>>>(src, dst, bcur, sorted, ovcnt, ovlist);
        kdeg  <<<NBK, 256, 0, stream>>>(bcur, sorted, ovcnt, ovlist, x, deg, dis, u);
        kq2   <<<NBK, 256, 0, stream>>>(bcur, sorted, ovcnt, ovlist, u, x, dis, deg, ad);
        khist <<<NBK, 256, 0, stream>>>(bcur, sorted, ovcnt, ovlist, ad, dt, meta, histA, histW);
        knode <<<(N_NODES + 63) / 64, 256, 0, stream>>>(histA, histW, meta, dt, tabs,
                                                        pw1, pb1, w2p, ad, b2, batch,
                                                        bcur, sorted, ovcnt, ovlist, pool, cnt);
        k7_mlp<<<G_GRAPHS, 64, 0, stream>>>(pool, cnt, fW1, fb1, fW2, fb2, out);
    } else {
        // fallback: R1 pipeline; agg1 in u, agg2 in the sorted/hist region
        float* agg1 = u;
        float* agg2 = (float*)(base + sorted_off);
        hipMemsetAsync(deg, 0, (size_t)N_NODES * 4, stream);
        hipMemsetAsync(pool, 0, (size_t)G_GRAPHS * HDIM * 4 + 1024, stream);
        kf1_deg<<<(N_EDGES + 255) / 256, 256, 0, stream>>>(dst, deg);
        kf2_dis<<<(N_NODES + 255) / 256, 256, 0, stream>>>(deg, x, dis, agg1);
        kf3_agg1<<<(N_EDGES + 255) / 256, 256, 0, stream>>>(src, dst, dis, x, agg1);
        kf4_agg2init<<<(N_NODES * HDIM + 255) / 256, 256, 0, stream>>>(agg1, dis, W1, b1, agg2);
        int k5_blocks = (int)(((long long)N_EDGES * HDIM + 255) / 256);
        kf5_edge<<<k5_blocks, 256, 0, stream>>>(src, dst, dis, agg1, W1, b1, agg2);
        kf6_pool<<<2048, 256, 0, stream>>>(agg2, W2, b2, batch, pool, cnt);
        k7_mlp<<<G_GRAPHS, 64, 0, stream>>>(pool, cnt, fW1, fb1, fW2, fb2, out);
    }
}